// Round 7
// baseline (473.435 us; speedup 1.0000x reference)
//
#include <hip/hip_runtime.h>

typedef _Float16 half8  __attribute__((ext_vector_type(8)));
typedef float    f32x4  __attribute__((ext_vector_type(4)));
typedef unsigned short ushort8 __attribute__((ext_vector_type(8)));

__device__ __forceinline__ float clampf(float v, float lo, float hi){
    return fminf(fmaxf(v, lo), hi);
}
__device__ __forceinline__ float b2f(unsigned short u){
    unsigned int x = ((unsigned int)u) << 16;
    return __builtin_bit_cast(float, x);
}
__device__ __forceinline__ unsigned short f2b(float f){
    unsigned int u = __builtin_bit_cast(unsigned int, f);
    u += 0x7FFFu + ((u >> 16) & 1u);       // round-to-nearest-even
    return (unsigned short)(u >> 16);
}

// ---------------------------------------------------------------------------
// ws layout in _Float16 ELEMENT offsets (all tensors stored as integer-valued f16)
#define EW_WALL 0u                       // [1536][512] packed Wq/Wk/Wv rows
#define EW_WO   786432u                  // [512][512]
#define EW_AQ   1048576u                 // [8192][512] act for q-proj
#define EW_AK   (EW_AQ + 4194304u)
#define EW_AV   (EW_AK + 4194304u)
#define EW_Q    (EW_AV + 4194304u)       // [bh=32][s=2048][d=64]
#define EW_K    (EW_Q  + 4194304u)       // [bh][s][d]
#define EW_VT   (EW_K  + 4194304u)       // [bh][d=64][s=2048]  (V transposed)
#define EW_O    (EW_VT + 4194304u)       // [8192][512]
// total = 30,408,704 elements = 60,817,408 bytes

// ---------------------------------------------------------------------------
__global__ __launch_bounds__(256) void k_quant_w(
    const unsigned short* __restrict__ Wq, const unsigned short* __restrict__ Wk,
    const unsigned short* __restrict__ Wv, const unsigned short* __restrict__ Wo,
    _Float16* __restrict__ w_all, _Float16* __restrict__ wo16,
    const unsigned short* __restrict__ scu)
{
    int gid  = blockIdx.x * 256 + threadIdx.x;   // 131072 threads, 8 elems each
    int idx8 = gid * 8;
    int which = idx8 >> 18;                      // 262144 elems per matrix
    int rem   = idx8 & 262143;
    const unsigned short* W = (which==0)? Wq : (which==1)? Wk : (which==2)? Wv : Wo;
    float sw = b2f((which<3) ? scu[2 + 2*which] : scu[13]);
    ushort8 w = *(const ushort8*)(W + rem);
    half8 o;
    #pragma unroll
    for (int j=0;j<8;j++)
        o[j] = (_Float16)rintf(clampf(b2f(w[j])/sw, -128.f, 127.f));
    _Float16* dst = (which<3) ? (w_all + which*262144 + rem) : (wo16 + rem);
    *(half8*)dst = o;
}

// ---------------------------------------------------------------------------
__global__ __launch_bounds__(256) void k_quant_a(
    const unsigned short* __restrict__ hs,
    _Float16* __restrict__ aq, _Float16* __restrict__ ak, _Float16* __restrict__ av,
    const unsigned short* __restrict__ scu)
{
    int gid = blockIdx.x * 256 + threadIdx.x;    // 524288 threads, 8 elems each
    int i8 = gid * 8;
    float s0 = b2f(scu[0]), s1 = b2f(scu[1]), s3 = b2f(scu[3]), s5 = b2f(scu[5]);
    ushort8 h = *(const ushort8*)(hs + i8);
    half8 q, k, v;
    #pragma unroll
    for (int j=0;j<8;j++){
        float h1 = rintf(clampf(b2f(h[j])/s0, -128.f, 127.f)) * s0;  // fq(hs, s0)
        q[j] = (_Float16)rintf(clampf(h1/s1, -128.f, 127.f));
        k[j] = (_Float16)rintf(clampf(h1/s3, -128.f, 127.f));
        v[j] = (_Float16)rintf(clampf(h1/s5, -128.f, 127.f));
    }
    *(half8*)(aq+i8) = q;
    *(half8*)(ak+i8) = k;
    *(half8*)(av+i8) = v;
}

// ---------------------------------------------------------------------------
// QKV projection: M=8192, N=1536 (3 projections x 512), K=512. 128x128 tiles,
// 4 waves each doing 64x64 via verified mfma_f32_16x16x32_f16 (exact int math).
__global__ __launch_bounds__(256) void k_gemm_qkv(
    const _Float16* __restrict__ aq, const _Float16* __restrict__ ak,
    const _Float16* __restrict__ av, const _Float16* __restrict__ w_all,
    _Float16* __restrict__ q16, _Float16* __restrict__ k16, _Float16* __restrict__ vt16,
    const unsigned short* __restrict__ scu)
{
    __shared__ __align__(16) _Float16 At[128][64];
    __shared__ __align__(16) _Float16 Bt[128][64];
    int tid = threadIdx.x;
    int m0 = blockIdx.x*128, n0 = blockIdx.y*128;
    int proj = blockIdx.y >> 2;                  // 4 n-blocks per projection
    const _Float16* Ag = (proj==0)? aq : (proj==1)? ak : av;
    int w = tid>>6, lane = tid&63, l15 = lane&15, quad = lane>>4;
    int wm = w>>1, wn = w&1;
    f32x4 z = {0.f,0.f,0.f,0.f};
    f32x4 acc[4][4];
    #pragma unroll
    for (int i=0;i<4;i++)
      #pragma unroll
      for (int j=0;j<4;j++) acc[i][j] = z;

    for (int k0=0; k0<512; k0+=64){
        #pragma unroll
        for (int it=0; it<4; it++){
            int idx = it*256 + tid;              // 0..1023
            int row = idx>>3, col = (idx&7)*8;
            *(half8*)(&At[row][col]) = *(const half8*)(Ag    + (m0+row)*512 + k0 + col);
            *(half8*)(&Bt[row][col]) = *(const half8*)(w_all + (n0+row)*512 + k0 + col);
        }
        __syncthreads();
        half8 af[4][2], bf[4][2];
        #pragma unroll
        for (int mt=0; mt<4; mt++){
            af[mt][0] = *(const half8*)(&At[wm*64+mt*16+l15][quad*8]);
            af[mt][1] = *(const half8*)(&At[wm*64+mt*16+l15][32+quad*8]);
        }
        #pragma unroll
        for (int nt=0; nt<4; nt++){
            bf[nt][0] = *(const half8*)(&Bt[wn*64+nt*16+l15][quad*8]);
            bf[nt][1] = *(const half8*)(&Bt[wn*64+nt*16+l15][32+quad*8]);
        }
        #pragma unroll
        for (int mt=0; mt<4; mt++)
          #pragma unroll
          for (int nt=0; nt<4; nt++){
            acc[mt][nt] = __builtin_amdgcn_mfma_f32_16x16x32_f16(af[mt][0], bf[nt][0], acc[mt][nt], 0,0,0);
            acc[mt][nt] = __builtin_amdgcn_mfma_f32_16x16x32_f16(af[mt][1], bf[nt][1], acc[mt][nt], 0,0,0);
          }
        __syncthreads();
    }

    float ssc = b2f(scu[1+2*proj]) * b2f(scu[2+2*proj]);
    float qs  = b2f((proj==0)? scu[7] : (proj==1)? scu[8] : scu[11]);
    #pragma unroll
    for (int mt=0; mt<4; mt++){
      #pragma unroll
      for (int nt=0; nt<4; nt++){
        int n = n0 + wn*64 + nt*16 + l15;        // C/D col = lane&15 (verified)
        int nloc = n & 511;
        int h = nloc>>6, d = nloc&63;
        #pragma unroll
        for (int r=0;r<4;r++){
          int m = m0 + wm*64 + mt*16 + quad*4 + r;   // C/D row = quad*4+reg (verified)
          int b = m>>11, s = m&2047;
          int bh = b*8 + h;
          float val = acc[mt][nt][r] * ssc;          // exact integer * scale
          float qv = rintf(clampf(val/qs, -128.f, 127.f));
          if (proj==0)      q16 [(bh*2048 + s)*64 + d] = (_Float16)qv;
          else if (proj==1) k16 [(bh*2048 + s)*64 + d] = (_Float16)qv;
          else              vt16[(bh*64 + d)*2048 + s] = (_Float16)qv;   // transposed
        }
      }
    }
}

// ---------------------------------------------------------------------------
// Fused attention, two-pass flash-style. ONE WAVE owns one (bh, 16-q-row) tile
// and the FULL t=2048 range — waves are fully independent (no __syncthreads).
// Pass 1: stream K tiles, QK^T MFMA, online (m,l) in log2 domain (8 regs),
//         then shuffle-merge (m,l) across the 16-lane column group.
// Pass 2: re-stream K, recompute scores (bit-identical MFMA), quantize P
//         (sc9 -> sc10, same chain as R6), wave-local LDS C->A transform
//         (lgkmcnt-ordered, barrier-free — verified R6), PV MFMA accumulate.
// R6 lesson: c[32] score cache cost 216 regs/wave -> 2 waves/SIMD -> pure
// latency stall (VALU 25%, MFMA 5%, HBM 4%). This version has no score
// storage: ~100 regs -> 4 waves/SIMD (work-limited), 2x occupancy.
// R4 lesson kept: all register arrays indexed by compile-time constants.
__global__ __launch_bounds__(256, 4) void k_attn(
    const _Float16* __restrict__ q16, const _Float16* __restrict__ k16,
    const _Float16* __restrict__ vt16, _Float16* __restrict__ o16,
    const unsigned short* __restrict__ scu)
{
    __shared__ __align__(16) _Float16 p16[4][16][72];  // per-wave P staging (+8 pad)
    int tid = threadIdx.x;
    int w = tid>>6, lane = tid&63, l15 = lane&15, quad = lane>>4;
    int task = blockIdx.x*4 + w;           // 4096 wave-tasks
    int bh = task >> 7;                    // 0..31
    int q0 = (task & 127) * 16;            // q-tile base
    float s9 = b2f(scu[9]), s10 = b2f(scu[10]);
    float alpha = b2f(scu[7]) * b2f(scu[8]) * 0.125f;    // DH^-0.5 = 0.125
    float al2 = alpha * 1.44269504088896341f;            // alpha * log2(e)

    f32x4 z = {0.f,0.f,0.f,0.f};
    const _Float16* qr = q16 + (bh*2048 + q0 + l15)*64;
    half8 aq0 = *(const half8*)(qr + quad*8);
    half8 aq1 = *(const half8*)(qr + 32 + quad*8);

    const _Float16* kbase = k16 + bh*131072 + l15*64;   // + tt*1024 per tile

    // ---- pass 1: online max/sum over 128 K-tiles (log2 domain) ----
    float m[4] = {-3.4e38f, -3.4e38f, -3.4e38f, -3.4e38f};
    float l[4] = {0.f, 0.f, 0.f, 0.f};
    #pragma unroll 4
    for (int tt=0; tt<128; tt++){
        const _Float16* kr = kbase + tt*1024;
        half8 bk0 = *(const half8*)(kr + quad*8);
        half8 bk1 = *(const half8*)(kr + 32 + quad*8);
        f32x4 s = __builtin_amdgcn_mfma_f32_16x16x32_f16(aq0, bk0, z, 0,0,0);
        s       = __builtin_amdgcn_mfma_f32_16x16x32_f16(aq1, bk1, s, 0,0,0);
        #pragma unroll
        for (int r=0;r<4;r++){
            float sc2 = s[r]*al2;                    // log2-units
            float M   = fmaxf(m[r], sc2);
            l[r] = fmaf(l[r], exp2f(m[r]-M), exp2f(sc2-M));
            m[r] = M;
        }
    }
    // merge (m,l) across the 16-lane column group
    #pragma unroll
    for (int r=0;r<4;r++){
        #pragma unroll
        for (int d=1; d<16; d<<=1){
            float mo = __shfl_xor(m[r], d, 64);
            float lo = __shfl_xor(l[r], d, 64);
            float M  = fmaxf(m[r], mo);
            l[r] = l[r]*exp2f(m[r]-M) + lo*exp2f(mo-M);
            m[r] = M;
        }
    }
    float inv_s9 = 1.0f / s9;
    float r910   = s9 / s10;
    float q9[4], mm2[4];
    #pragma unroll
    for (int r=0;r<4;r++){ q9[r] = inv_s9 / l[r]; mm2[r] = m[r]; }

    // ---- pass 2: recompute scores, quantize P, PV accumulate ----
    f32x4 oacc[4];
    #pragma unroll
    for (int dt=0; dt<4; dt++) oacc[dt] = z;
    const _Float16* vbase = vt16 + bh*131072;
    for (int ch=0; ch<32; ch++){
        #pragma unroll
        for (int j=0;j<4;j++){
            const _Float16* kr = kbase + (ch*4+j)*1024;
            half8 bk0 = *(const half8*)(kr + quad*8);
            half8 bk1 = *(const half8*)(kr + 32 + quad*8);
            f32x4 s = __builtin_amdgcn_mfma_f32_16x16x32_f16(aq0, bk0, z, 0,0,0);
            s       = __builtin_amdgcn_mfma_f32_16x16x32_f16(aq1, bk1, s, 0,0,0);
            #pragma unroll
            for (int r=0;r<4;r++){
                float e   = exp2f(s[r]*al2 - mm2[r]);
                float p1i = rintf(fminf(e*q9[r], 255.f));    // fq(softmax,s9,0,255) int
                float a   = rintf(fminf(p1i*r910, 127.f));   // fq(.,s10) int
                p16[w][quad*4+r][j*16+l15] = (_Float16)a;    // [qrow][tloc]
            }
        }
        half8 ap0 = *(const half8*)(&p16[w][l15][quad*8]);
        half8 ap1 = *(const half8*)(&p16[w][l15][32+quad*8]);
        #pragma unroll
        for (int dt=0; dt<4; dt++){
            const _Float16* vr = vbase + (dt*16 + l15)*2048 + ch*64;
            half8 bv0 = *(const half8*)(vr + quad*8);
            half8 bv1 = *(const half8*)(vr + 32 + quad*8);
            oacc[dt] = __builtin_amdgcn_mfma_f32_16x16x32_f16(ap0, bv0, oacc[dt], 0,0,0);
            oacc[dt] = __builtin_amdgcn_mfma_f32_16x16x32_f16(ap1, bv1, oacc[dt], 0,0,0);
        }
    }

    // ---- epilogue: quantize with sc12, direct C-layout stores ----
    float s1011 = b2f(scu[10]) * b2f(scu[11]);
    float s12   = b2f(scu[12]);
    int b = bh>>3, h = bh&7;
    #pragma unroll
    for (int dt=0; dt<4; dt++){
        #pragma unroll
        for (int r=0;r<4;r++){
            float o = oacc[dt][r] * s1011;
            _Float16 v = (_Float16)rintf(clampf(o/s12, -128.f, 127.f));
            o16[(b*2048 + q0 + quad*4 + r)*512 + h*64 + dt*16 + l15] = v;
        }
    }
}

// ---------------------------------------------------------------------------
// Output projection: M=8192, N=512, K=512, + bias, bf16 out.
__global__ __launch_bounds__(256) void k_gemm_out(
    const _Float16* __restrict__ o16, const _Float16* __restrict__ wo16,
    const unsigned short* __restrict__ bo, unsigned short* __restrict__ out,
    const unsigned short* __restrict__ scu)
{
    __shared__ __align__(16) _Float16 At[128][64];
    __shared__ __align__(16) _Float16 Bt[128][64];
    int tid = threadIdx.x;
    int m0 = blockIdx.x*128, n0 = blockIdx.y*128;
    int w = tid>>6, lane = tid&63, l15 = lane&15, quad = lane>>4;
    int wm = w>>1, wn = w&1;
    f32x4 z = {0.f,0.f,0.f,0.f};
    f32x4 acc[4][4];
    #pragma unroll
    for (int i=0;i<4;i++)
      #pragma unroll
      for (int j=0;j<4;j++) acc[i][j] = z;

    for (int k0=0; k0<512; k0+=64){
        #pragma unroll
        for (int it=0; it<4; it++){
            int idx = it*256 + tid;
            int row = idx>>3, col = (idx&7)*8;
            *(half8*)(&At[row][col]) = *(const half8*)(o16  + (m0+row)*512 + k0 + col);
            *(half8*)(&Bt[row][col]) = *(const half8*)(wo16 + (n0+row)*512 + k0 + col);
        }
        __syncthreads();
        half8 af[4][2], bf[4][2];
        #pragma unroll
        for (int mt=0; mt<4; mt++){
            af[mt][0] = *(const half8*)(&At[wm*64+mt*16+l15][quad*8]);
            af[mt][1] = *(const half8*)(&At[wm*64+mt*16+l15][32+quad*8]);
        }
        #pragma unroll
        for (int nt=0; nt<4; nt++){
            bf[nt][0] = *(const half8*)(&Bt[wn*64+nt*16+l15][quad*8]);
            bf[nt][1] = *(const half8*)(&Bt[wn*64+nt*16+l15][32+quad*8]);
        }
        #pragma unroll
        for (int mt=0; mt<4; mt++)
          #pragma unroll
          for (int nt=0; nt<4; nt++){
            acc[mt][nt] = __builtin_amdgcn_mfma_f32_16x16x32_f16(af[mt][0], bf[nt][0], acc[mt][nt], 0,0,0);
            acc[mt][nt] = __builtin_amdgcn_mfma_f32_16x16x32_f16(af[mt][1], bf[nt][1], acc[mt][nt], 0,0,0);
          }
        __syncthreads();
    }

    float ssc = b2f(scu[12]) * b2f(scu[13]);
    #pragma unroll
    for (int mt=0; mt<4; mt++){
      #pragma unroll
      for (int nt=0; nt<4; nt++){
        int n = n0 + wn*64 + nt*16 + l15;
        float bn = b2f(bo[n]);
        #pragma unroll
        for (int r=0;r<4;r++){
          int m = m0 + wm*64 + mt*16 + quad*4 + r;
          out[m*512 + n] = f2b(acc[mt][nt][r]*ssc + bn);
        }
      }
    }
}

// ---------------------------------------------------------------------------
extern "C" void kernel_launch(void* const* d_in, const int* in_sizes, int n_in,
                              void* d_out, int out_size, void* d_ws, size_t ws_size,
                              hipStream_t stream)
{
    const unsigned short* hs = (const unsigned short*)d_in[0];
    const unsigned short* Wq = (const unsigned short*)d_in[1];
    const unsigned short* Wk = (const unsigned short*)d_in[2];
    const unsigned short* Wv = (const unsigned short*)d_in[3];
    const unsigned short* Wo = (const unsigned short*)d_in[4];
    const unsigned short* bo = (const unsigned short*)d_in[5];
    const unsigned short* sc = (const unsigned short*)d_in[6];
    unsigned short* out = (unsigned short*)d_out;

    _Float16* wsh   = (_Float16*)d_ws;
    _Float16* w_all = wsh + EW_WALL;
    _Float16* wo16  = wsh + EW_WO;
    _Float16* a_q   = wsh + EW_AQ;
    _Float16* a_k   = wsh + EW_AK;
    _Float16* a_v   = wsh + EW_AV;
    _Float16* q16   = wsh + EW_Q;
    _Float16* k16   = wsh + EW_K;
    _Float16* vt16  = wsh + EW_VT;
    _Float16* o16   = wsh + EW_O;

    k_quant_w<<<512,  256, 0, stream>>>(Wq, Wk, Wv, Wo, w_all, wo16, sc);
    k_quant_a<<<2048, 256, 0, stream>>>(hs, a_q, a_k, a_v, sc);
    k_gemm_qkv<<<dim3(64,12), 256, 0, stream>>>(a_q, a_k, a_v, w_all, q16, k16, vt16, sc);
    k_attn<<<1024, 256, 0, stream>>>(q16, k16, vt16, o16, sc);
    k_gemm_out<<<dim3(64,4), 256, 0, stream>>>(o16, wo16, bo, out, sc);
}

// Round 8
// 312.795 us; speedup vs baseline: 1.5136x; 1.5136x over previous
//
#include <hip/hip_runtime.h>

typedef _Float16 half8  __attribute__((ext_vector_type(8)));
typedef float    f32x4  __attribute__((ext_vector_type(4)));
typedef unsigned short ushort8 __attribute__((ext_vector_type(8)));

__device__ __forceinline__ float clampf(float v, float lo, float hi){
    return fminf(fmaxf(v, lo), hi);
}
__device__ __forceinline__ float b2f(unsigned short u){
    unsigned int x = ((unsigned int)u) << 16;
    return __builtin_bit_cast(float, x);
}
__device__ __forceinline__ unsigned short f2b(float f){
    unsigned int u = __builtin_bit_cast(unsigned int, f);
    u += 0x7FFFu + ((u >> 16) & 1u);       // round-to-nearest-even
    return (unsigned short)(u >> 16);
}

// ---------------------------------------------------------------------------
// ws layout in _Float16 ELEMENT offsets (all tensors stored as integer-valued f16)
#define EW_WALL 0u                       // [1536][512] packed Wq/Wk/Wv rows
#define EW_WO   786432u                  // [512][512]
#define EW_AQ   1048576u                 // [8192][512] act for q-proj
#define EW_AK   (EW_AQ + 4194304u)
#define EW_AV   (EW_AK + 4194304u)
#define EW_Q    (EW_AV + 4194304u)       // [bh=32][s=2048][d=64]
#define EW_K    (EW_Q  + 4194304u)       // [bh][s][d]
#define EW_VT   (EW_K  + 4194304u)       // [bh][d=64][s=2048]  (V transposed)
#define EW_O    (EW_VT + 4194304u)       // [8192][512]
// total = 30,408,704 elements = 60,817,408 bytes

// ---------------------------------------------------------------------------
__global__ __launch_bounds__(256) void k_quant_w(
    const unsigned short* __restrict__ Wq, const unsigned short* __restrict__ Wk,
    const unsigned short* __restrict__ Wv, const unsigned short* __restrict__ Wo,
    _Float16* __restrict__ w_all, _Float16* __restrict__ wo16,
    const unsigned short* __restrict__ scu)
{
    int gid  = blockIdx.x * 256 + threadIdx.x;   // 131072 threads, 8 elems each
    int idx8 = gid * 8;
    int which = idx8 >> 18;                      // 262144 elems per matrix
    int rem   = idx8 & 262143;
    const unsigned short* W = (which==0)? Wq : (which==1)? Wk : (which==2)? Wv : Wo;
    float sw = b2f((which<3) ? scu[2 + 2*which] : scu[13]);
    ushort8 w = *(const ushort8*)(W + rem);
    half8 o;
    #pragma unroll
    for (int j=0;j<8;j++)
        o[j] = (_Float16)rintf(clampf(b2f(w[j])/sw, -128.f, 127.f));
    _Float16* dst = (which<3) ? (w_all + which*262144 + rem) : (wo16 + rem);
    *(half8*)dst = o;
}

// ---------------------------------------------------------------------------
__global__ __launch_bounds__(256) void k_quant_a(
    const unsigned short* __restrict__ hs,
    _Float16* __restrict__ aq, _Float16* __restrict__ ak, _Float16* __restrict__ av,
    const unsigned short* __restrict__ scu)
{
    int gid = blockIdx.x * 256 + threadIdx.x;    // 524288 threads, 8 elems each
    int i8 = gid * 8;
    float s0 = b2f(scu[0]), s1 = b2f(scu[1]), s3 = b2f(scu[3]), s5 = b2f(scu[5]);
    ushort8 h = *(const ushort8*)(hs + i8);
    half8 q, k, v;
    #pragma unroll
    for (int j=0;j<8;j++){
        float h1 = rintf(clampf(b2f(h[j])/s0, -128.f, 127.f)) * s0;  // fq(hs, s0)
        q[j] = (_Float16)rintf(clampf(h1/s1, -128.f, 127.f));
        k[j] = (_Float16)rintf(clampf(h1/s3, -128.f, 127.f));
        v[j] = (_Float16)rintf(clampf(h1/s5, -128.f, 127.f));
    }
    *(half8*)(aq+i8) = q;
    *(half8*)(ak+i8) = k;
    *(half8*)(av+i8) = v;
}

// ---------------------------------------------------------------------------
// QKV projection: M=8192, N=1536 (3 projections x 512), K=512. 128x128 tiles,
// 4 waves each doing 64x64 via verified mfma_f32_16x16x32_f16 (exact int math).
__global__ __launch_bounds__(256) void k_gemm_qkv(
    const _Float16* __restrict__ aq, const _Float16* __restrict__ ak,
    const _Float16* __restrict__ av, const _Float16* __restrict__ w_all,
    _Float16* __restrict__ q16, _Float16* __restrict__ k16, _Float16* __restrict__ vt16,
    const unsigned short* __restrict__ scu)
{
    __shared__ __align__(16) _Float16 At[128][64];
    __shared__ __align__(16) _Float16 Bt[128][64];
    int tid = threadIdx.x;
    int m0 = blockIdx.x*128, n0 = blockIdx.y*128;
    int proj = blockIdx.y >> 2;                  // 4 n-blocks per projection
    const _Float16* Ag = (proj==0)? aq : (proj==1)? ak : av;
    int w = tid>>6, lane = tid&63, l15 = lane&15, quad = lane>>4;
    int wm = w>>1, wn = w&1;
    f32x4 z = {0.f,0.f,0.f,0.f};
    f32x4 acc[4][4];
    #pragma unroll
    for (int i=0;i<4;i++)
      #pragma unroll
      for (int j=0;j<4;j++) acc[i][j] = z;

    for (int k0=0; k0<512; k0+=64){
        #pragma unroll
        for (int it=0; it<4; it++){
            int idx = it*256 + tid;              // 0..1023
            int row = idx>>3, col = (idx&7)*8;
            *(half8*)(&At[row][col]) = *(const half8*)(Ag    + (m0+row)*512 + k0 + col);
            *(half8*)(&Bt[row][col]) = *(const half8*)(w_all + (n0+row)*512 + k0 + col);
        }
        __syncthreads();
        half8 af[4][2], bf[4][2];
        #pragma unroll
        for (int mt=0; mt<4; mt++){
            af[mt][0] = *(const half8*)(&At[wm*64+mt*16+l15][quad*8]);
            af[mt][1] = *(const half8*)(&At[wm*64+mt*16+l15][32+quad*8]);
        }
        #pragma unroll
        for (int nt=0; nt<4; nt++){
            bf[nt][0] = *(const half8*)(&Bt[wn*64+nt*16+l15][quad*8]);
            bf[nt][1] = *(const half8*)(&Bt[wn*64+nt*16+l15][32+quad*8]);
        }
        #pragma unroll
        for (int mt=0; mt<4; mt++)
          #pragma unroll
          for (int nt=0; nt<4; nt++){
            acc[mt][nt] = __builtin_amdgcn_mfma_f32_16x16x32_f16(af[mt][0], bf[nt][0], acc[mt][nt], 0,0,0);
            acc[mt][nt] = __builtin_amdgcn_mfma_f32_16x16x32_f16(af[mt][1], bf[nt][1], acc[mt][nt], 0,0,0);
          }
        __syncthreads();
    }

    float ssc = b2f(scu[1+2*proj]) * b2f(scu[2+2*proj]);
    float qs  = b2f((proj==0)? scu[7] : (proj==1)? scu[8] : scu[11]);
    #pragma unroll
    for (int mt=0; mt<4; mt++){
      #pragma unroll
      for (int nt=0; nt<4; nt++){
        int n = n0 + wn*64 + nt*16 + l15;        // C/D col = lane&15 (verified)
        int nloc = n & 511;
        int h = nloc>>6, d = nloc&63;
        #pragma unroll
        for (int r=0;r<4;r++){
          int m = m0 + wm*64 + mt*16 + quad*4 + r;   // C/D row = quad*4+reg (verified)
          int b = m>>11, s = m&2047;
          int bh = b*8 + h;
          float val = acc[mt][nt][r] * ssc;          // exact integer * scale
          float qv = rintf(clampf(val/qs, -128.f, 127.f));
          if (proj==0)      q16 [(bh*2048 + s)*64 + d] = (_Float16)qv;
          else if (proj==1) k16 [(bh*2048 + s)*64 + d] = (_Float16)qv;
          else              vt16[(bh*64 + d)*2048 + s] = (_Float16)qv;   // transposed
        }
      }
    }
}

// ---------------------------------------------------------------------------
// Fused attention v3: block = 4 waves = one (bh, 64 q-rows); wave w owns
// q rows [q0, q0+16) exclusively -> softmax state is per-wave (no cross-wave
// reduction). Two passes over t in 128-t chunks with block-cooperative,
// double-buffered LDS staging of K (coalesced 16B loads issued one full
// chunk ahead; 1 barrier/chunk). Pass 1: chunk-local max/sum merged into
// running (m,l) (breaks R7's per-tile serial exp chain); lane-shuffle merge.
// Pass 2: recompute QK from the SAME staged LDS data (bit-identical),
// quantize P (sc9->sc10 chain), wave-local LDS C->A transform (barrier-free,
// in-order DS — verified R6/R7), PV MFMA with V fragments prefetched into
// registers at chunk start (shared across waves via L1).
// R7 lesson: per-wave serial global loads -> ~700k cyc exposed latency;
// this staging structure keeps ~16KB in flight per block instead.
__global__ __launch_bounds__(256, 3) void k_attn(
    const _Float16* __restrict__ q16, const _Float16* __restrict__ k16,
    const _Float16* __restrict__ vt16, _Float16* __restrict__ o16,
    const unsigned short* __restrict__ scu)
{
    __shared__ __align__(16) _Float16 Kbuf[2][128][72];  // +8 pad: conflict-minimal reads
    __shared__ __align__(16) _Float16 p16[4][16][72];    // per-wave P staging
    int tid = threadIdx.x;
    int w = tid>>6, lane = tid&63, l15 = lane&15, quad = lane>>4;
    int bh = blockIdx.y;
    int q0 = blockIdx.x*64 + w*16;
    float s9 = b2f(scu[9]), s10 = b2f(scu[10]);
    float alpha = b2f(scu[7]) * b2f(scu[8]) * 0.125f;    // DH^-0.5
    float al2 = alpha * 1.44269504088896341f;            // alpha * log2(e)

    f32x4 z = {0.f,0.f,0.f,0.f};
    const _Float16* qr = q16 + (bh*2048 + q0 + l15)*64;
    half8 aq0 = *(const half8*)(qr + quad*8);
    half8 aq1 = *(const half8*)(qr + 32 + quad*8);

    const _Float16* kg    = k16  + bh*131072;
    const _Float16* vbase = vt16 + bh*131072;
    int srow = tid>>3, scol = (tid&7)*8;     // staging coords for this thread

    half8 kst[4];
    #pragma unroll
    for (int i=0;i<4;i++) kst[i] = *(const half8*)(kg + i*2048 + tid*8);  // chunk 0

    float m[4], l[4];
    #pragma unroll
    for (int r=0;r<4;r++){ m[r] = -3.4e38f; l[r] = 0.f; }

    // ---- pass 1: online (m,l) over 16 staged chunks ----
    for (int ch=0; ch<16; ch++){
        int buf = ch & 1;
        #pragma unroll
        for (int i=0;i<4;i++) *(half8*)(&Kbuf[buf][srow + i*32][scol]) = kst[i];
        const _Float16* nsrc = kg + ((ch==15)? 0 : (ch+1))*8192;   // ch15 preloads pass-2 chunk 0
        #pragma unroll
        for (int i=0;i<4;i++) kst[i] = *(const half8*)(nsrc + i*2048 + tid*8);
        __syncthreads();
        #pragma unroll
        for (int sub=0; sub<2; sub++){
            f32x4 s[4];
            #pragma unroll
            for (int j=0;j<4;j++){
                int tt = sub*4 + j;
                half8 bk0 = *(const half8*)(&Kbuf[buf][tt*16+l15][quad*8]);
                half8 bk1 = *(const half8*)(&Kbuf[buf][tt*16+l15][32+quad*8]);
                f32x4 t = __builtin_amdgcn_mfma_f32_16x16x32_f16(aq0, bk0, z, 0,0,0);
                s[j]    = __builtin_amdgcn_mfma_f32_16x16x32_f16(aq1, bk1, t, 0,0,0);
            }
            #pragma unroll
            for (int r=0;r<4;r++){
                float a0 = s[0][r]*al2, a1 = s[1][r]*al2;
                float a2 = s[2][r]*al2, a3 = s[3][r]*al2;
                float mc = fmaxf(fmaxf(a0,a1), fmaxf(a2,a3));
                float lc = exp2f(a0-mc) + exp2f(a1-mc) + exp2f(a2-mc) + exp2f(a3-mc);
                float M  = fmaxf(m[r], mc);
                l[r] = l[r]*exp2f(m[r]-M) + lc*exp2f(mc-M);
                m[r] = M;
            }
        }
    }

    // merge (m,l) across the 16 column lanes (quad preserved: d<16)
    #pragma unroll
    for (int r=0;r<4;r++){
        #pragma unroll
        for (int d=1; d<16; d<<=1){
            float mo = __shfl_xor(m[r], d, 64);
            float lo = __shfl_xor(l[r], d, 64);
            float M  = fmaxf(m[r], mo);
            l[r] = l[r]*exp2f(m[r]-M) + lo*exp2f(mo-M);
            m[r] = M;
        }
    }
    float inv_s9 = 1.0f / s9;
    float r910   = s9 / s10;
    float q9[4], mm2[4];
    #pragma unroll
    for (int r=0;r<4;r++){ q9[r] = inv_s9 / l[r]; mm2[r] = m[r]; }

    // ---- pass 2: recompute scores from re-staged K, quantize P, PV ----
    f32x4 oacc[4];
    #pragma unroll
    for (int dt=0; dt<4; dt++) oacc[dt] = z;
    for (int ch=0; ch<16; ch++){
        int buf = ch & 1;
        #pragma unroll
        for (int i=0;i<4;i++) *(half8*)(&Kbuf[buf][srow + i*32][scol]) = kst[i];
        if (ch < 15){
            const _Float16* nsrc = kg + (ch+1)*8192;
            #pragma unroll
            for (int i=0;i<4;i++) kst[i] = *(const half8*)(nsrc + i*2048 + tid*8);
        }
        __syncthreads();
        // prefetch V fragments for both 64-t subgroups of this chunk
        half8 bva[8], bvb[8];
        #pragma unroll
        for (int dt=0; dt<4; dt++){
            const _Float16* vr0 = vbase + (dt*16+l15)*2048 + ch*128;
            bva[dt*2]   = *(const half8*)(vr0 + quad*8);
            bva[dt*2+1] = *(const half8*)(vr0 + 32 + quad*8);
            bvb[dt*2]   = *(const half8*)(vr0 + 64 + quad*8);
            bvb[dt*2+1] = *(const half8*)(vr0 + 96 + quad*8);
        }
        #pragma unroll
        for (int sub=0; sub<2; sub++){
            f32x4 s[4];
            #pragma unroll
            for (int j=0;j<4;j++){
                int tt = sub*4 + j;
                half8 bk0 = *(const half8*)(&Kbuf[buf][tt*16+l15][quad*8]);
                half8 bk1 = *(const half8*)(&Kbuf[buf][tt*16+l15][32+quad*8]);
                f32x4 t = __builtin_amdgcn_mfma_f32_16x16x32_f16(aq0, bk0, z, 0,0,0);
                s[j]    = __builtin_amdgcn_mfma_f32_16x16x32_f16(aq1, bk1, t, 0,0,0);
            }
            #pragma unroll
            for (int j=0;j<4;j++){
                #pragma unroll
                for (int r=0;r<4;r++){
                    float e   = exp2f(s[j][r]*al2 - mm2[r]);
                    float p1i = rintf(fminf(e*q9[r], 255.f));    // fq(softmax,s9,0,255) int
                    float a   = rintf(fminf(p1i*r910, 127.f));   // fq(.,s10) int
                    p16[w][quad*4+r][j*16+l15] = (_Float16)a;
                }
            }
            half8 ap0 = *(const half8*)(&p16[w][l15][quad*8]);
            half8 ap1 = *(const half8*)(&p16[w][l15][32+quad*8]);
            #pragma unroll
            for (int dt=0; dt<4; dt++){
                half8 b0 = sub ? bvb[dt*2]   : bva[dt*2];
                half8 b1 = sub ? bvb[dt*2+1] : bva[dt*2+1];
                oacc[dt] = __builtin_amdgcn_mfma_f32_16x16x32_f16(ap0, b0, oacc[dt], 0,0,0);
                oacc[dt] = __builtin_amdgcn_mfma_f32_16x16x32_f16(ap1, b1, oacc[dt], 0,0,0);
            }
        }
    }

    // ---- epilogue: quantize with sc12, direct C-layout stores ----
    float s1011 = b2f(scu[10]) * b2f(scu[11]);
    float s12   = b2f(scu[12]);
    int b = bh>>3, h = bh&7;
    #pragma unroll
    for (int dt=0; dt<4; dt++){
        #pragma unroll
        for (int r=0;r<4;r++){
            float o = oacc[dt][r] * s1011;
            _Float16 v = (_Float16)rintf(clampf(o/s12, -128.f, 127.f));
            o16[(b*2048 + q0 + quad*4 + r)*512 + h*64 + dt*16 + l15] = v;
        }
    }
}

// ---------------------------------------------------------------------------
// Output projection: M=8192, N=512, K=512, + bias, bf16 out.
__global__ __launch_bounds__(256) void k_gemm_out(
    const _Float16* __restrict__ o16, const _Float16* __restrict__ wo16,
    const unsigned short* __restrict__ bo, unsigned short* __restrict__ out,
    const unsigned short* __restrict__ scu)
{
    __shared__ __align__(16) _Float16 At[128][64];
    __shared__ __align__(16) _Float16 Bt[128][64];
    int tid = threadIdx.x;
    int m0 = blockIdx.x*128, n0 = blockIdx.y*128;
    int w = tid>>6, lane = tid&63, l15 = lane&15, quad = lane>>4;
    int wm = w>>1, wn = w&1;
    f32x4 z = {0.f,0.f,0.f,0.f};
    f32x4 acc[4][4];
    #pragma unroll
    for (int i=0;i<4;i++)
      #pragma unroll
      for (int j=0;j<4;j++) acc[i][j] = z;

    for (int k0=0; k0<512; k0+=64){
        #pragma unroll
        for (int it=0; it<4; it++){
            int idx = it*256 + tid;
            int row = idx>>3, col = (idx&7)*8;
            *(half8*)(&At[row][col]) = *(const half8*)(o16  + (m0+row)*512 + k0 + col);
            *(half8*)(&Bt[row][col]) = *(const half8*)(wo16 + (n0+row)*512 + k0 + col);
        }
        __syncthreads();
        half8 af[4][2], bf[4][2];
        #pragma unroll
        for (int mt=0; mt<4; mt++){
            af[mt][0] = *(const half8*)(&At[wm*64+mt*16+l15][quad*8]);
            af[mt][1] = *(const half8*)(&At[wm*64+mt*16+l15][32+quad*8]);
        }
        #pragma unroll
        for (int nt=0; nt<4; nt++){
            bf[nt][0] = *(const half8*)(&Bt[wn*64+nt*16+l15][quad*8]);
            bf[nt][1] = *(const half8*)(&Bt[wn*64+nt*16+l15][32+quad*8]);
        }
        #pragma unroll
        for (int mt=0; mt<4; mt++)
          #pragma unroll
          for (int nt=0; nt<4; nt++){
            acc[mt][nt] = __builtin_amdgcn_mfma_f32_16x16x32_f16(af[mt][0], bf[nt][0], acc[mt][nt], 0,0,0);
            acc[mt][nt] = __builtin_amdgcn_mfma_f32_16x16x32_f16(af[mt][1], bf[nt][1], acc[mt][nt], 0,0,0);
          }
        __syncthreads();
    }

    float ssc = b2f(scu[12]) * b2f(scu[13]);
    #pragma unroll
    for (int mt=0; mt<4; mt++){
      #pragma unroll
      for (int nt=0; nt<4; nt++){
        int n = n0 + wn*64 + nt*16 + l15;
        float bn = b2f(bo[n]);
        #pragma unroll
        for (int r=0;r<4;r++){
          int m = m0 + wm*64 + mt*16 + quad*4 + r;
          out[m*512 + n] = f2b(acc[mt][nt][r]*ssc + bn);
        }
      }
    }
}

// ---------------------------------------------------------------------------
extern "C" void kernel_launch(void* const* d_in, const int* in_sizes, int n_in,
                              void* d_out, int out_size, void* d_ws, size_t ws_size,
                              hipStream_t stream)
{
    const unsigned short* hs = (const unsigned short*)d_in[0];
    const unsigned short* Wq = (const unsigned short*)d_in[1];
    const unsigned short* Wk = (const unsigned short*)d_in[2];
    const unsigned short* Wv = (const unsigned short*)d_in[3];
    const unsigned short* Wo = (const unsigned short*)d_in[4];
    const unsigned short* bo = (const unsigned short*)d_in[5];
    const unsigned short* sc = (const unsigned short*)d_in[6];
    unsigned short* out = (unsigned short*)d_out;

    _Float16* wsh   = (_Float16*)d_ws;
    _Float16* w_all = wsh + EW_WALL;
    _Float16* wo16  = wsh + EW_WO;
    _Float16* a_q   = wsh + EW_AQ;
    _Float16* a_k   = wsh + EW_AK;
    _Float16* a_v   = wsh + EW_AV;
    _Float16* q16   = wsh + EW_Q;
    _Float16* k16   = wsh + EW_K;
    _Float16* vt16  = wsh + EW_VT;
    _Float16* o16   = wsh + EW_O;

    k_quant_w<<<512,  256, 0, stream>>>(Wq, Wk, Wv, Wo, w_all, wo16, sc);
    k_quant_a<<<2048, 256, 0, stream>>>(hs, a_q, a_k, a_v, sc);
    k_gemm_qkv<<<dim3(64,12), 256, 0, stream>>>(a_q, a_k, a_v, w_all, q16, k16, vt16, sc);
    k_attn<<<dim3(32,32), 256, 0, stream>>>(q16, k16, vt16, o16, sc);
    k_gemm_out<<<dim3(64,4), 256, 0, stream>>>(o16, wo16, bo, out, sc);
}

// Round 9
// 295.709 us; speedup vs baseline: 1.6010x; 1.0578x over previous
//
#include <hip/hip_runtime.h>

typedef _Float16 half8  __attribute__((ext_vector_type(8)));
typedef float    f32x4  __attribute__((ext_vector_type(4)));
typedef unsigned short ushort8 __attribute__((ext_vector_type(8)));

__device__ __forceinline__ float clampf(float v, float lo, float hi){
    return fminf(fmaxf(v, lo), hi);
}
__device__ __forceinline__ float b2f(unsigned short u){
    unsigned int x = ((unsigned int)u) << 16;
    return __builtin_bit_cast(float, x);
}
__device__ __forceinline__ unsigned short f2b(float f){
    unsigned int u = __builtin_bit_cast(unsigned int, f);
    u += 0x7FFFu + ((u >> 16) & 1u);       // round-to-nearest-even
    return (unsigned short)(u >> 16);
}

// ---------------------------------------------------------------------------
// ws layout in _Float16 ELEMENT offsets (all tensors stored as integer-valued f16)
#define EW_WALL 0u                       // [1536][512] packed Wq/Wk/Wv rows
#define EW_WO   786432u                  // [512][512]
#define EW_AQ   1048576u                 // [8192][512] act for q-proj
#define EW_AK   (EW_AQ + 4194304u)
#define EW_AV   (EW_AK + 4194304u)
#define EW_Q    (EW_AV + 4194304u)       // [bh=32][s=2048][d=64]
#define EW_K    (EW_Q  + 4194304u)       // [bh][s][d]
#define EW_VT   (EW_K  + 4194304u)       // [bh][d=64][s=2048]  (V transposed)
#define EW_O    (EW_VT + 4194304u)       // [8192][512]
// total = 30,408,704 elements = 60,817,408 bytes

// ---------------------------------------------------------------------------
__global__ __launch_bounds__(256) void k_quant_w(
    const unsigned short* __restrict__ Wq, const unsigned short* __restrict__ Wk,
    const unsigned short* __restrict__ Wv, const unsigned short* __restrict__ Wo,
    _Float16* __restrict__ w_all, _Float16* __restrict__ wo16,
    const unsigned short* __restrict__ scu)
{
    int gid  = blockIdx.x * 256 + threadIdx.x;   // 131072 threads, 8 elems each
    int idx8 = gid * 8;
    int which = idx8 >> 18;                      // 262144 elems per matrix
    int rem   = idx8 & 262143;
    const unsigned short* W = (which==0)? Wq : (which==1)? Wk : (which==2)? Wv : Wo;
    float sw = b2f((which<3) ? scu[2 + 2*which] : scu[13]);
    ushort8 w = *(const ushort8*)(W + rem);
    half8 o;
    #pragma unroll
    for (int j=0;j<8;j++)
        o[j] = (_Float16)rintf(clampf(b2f(w[j])/sw, -128.f, 127.f));
    _Float16* dst = (which<3) ? (w_all + which*262144 + rem) : (wo16 + rem);
    *(half8*)dst = o;
}

// ---------------------------------------------------------------------------
__global__ __launch_bounds__(256) void k_quant_a(
    const unsigned short* __restrict__ hs,
    _Float16* __restrict__ aq, _Float16* __restrict__ ak, _Float16* __restrict__ av,
    const unsigned short* __restrict__ scu)
{
    int gid = blockIdx.x * 256 + threadIdx.x;    // 524288 threads, 8 elems each
    int i8 = gid * 8;
    float s0 = b2f(scu[0]), s1 = b2f(scu[1]), s3 = b2f(scu[3]), s5 = b2f(scu[5]);
    ushort8 h = *(const ushort8*)(hs + i8);
    half8 q, k, v;
    #pragma unroll
    for (int j=0;j<8;j++){
        float h1 = rintf(clampf(b2f(h[j])/s0, -128.f, 127.f)) * s0;  // fq(hs, s0)
        q[j] = (_Float16)rintf(clampf(h1/s1, -128.f, 127.f));
        k[j] = (_Float16)rintf(clampf(h1/s3, -128.f, 127.f));
        v[j] = (_Float16)rintf(clampf(h1/s5, -128.f, 127.f));
    }
    *(half8*)(aq+i8) = q;
    *(half8*)(ak+i8) = k;
    *(half8*)(av+i8) = v;
}

// ---------------------------------------------------------------------------
// QKV projection: M=8192, N=1536 (3 projections x 512), K=512. 128x128 tiles,
// 4 waves each doing 64x64 via verified mfma_f32_16x16x32_f16 (exact int math).
__global__ __launch_bounds__(256) void k_gemm_qkv(
    const _Float16* __restrict__ aq, const _Float16* __restrict__ ak,
    const _Float16* __restrict__ av, const _Float16* __restrict__ w_all,
    _Float16* __restrict__ q16, _Float16* __restrict__ k16, _Float16* __restrict__ vt16,
    const unsigned short* __restrict__ scu)
{
    __shared__ __align__(16) _Float16 At[128][64];
    __shared__ __align__(16) _Float16 Bt[128][64];
    int tid = threadIdx.x;
    int m0 = blockIdx.x*128, n0 = blockIdx.y*128;
    int proj = blockIdx.y >> 2;                  // 4 n-blocks per projection
    const _Float16* Ag = (proj==0)? aq : (proj==1)? ak : av;
    int w = tid>>6, lane = tid&63, l15 = lane&15, quad = lane>>4;
    int wm = w>>1, wn = w&1;
    f32x4 z = {0.f,0.f,0.f,0.f};
    f32x4 acc[4][4];
    #pragma unroll
    for (int i=0;i<4;i++)
      #pragma unroll
      for (int j=0;j<4;j++) acc[i][j] = z;

    for (int k0=0; k0<512; k0+=64){
        #pragma unroll
        for (int it=0; it<4; it++){
            int idx = it*256 + tid;              // 0..1023
            int row = idx>>3, col = (idx&7)*8;
            *(half8*)(&At[row][col]) = *(const half8*)(Ag    + (m0+row)*512 + k0 + col);
            *(half8*)(&Bt[row][col]) = *(const half8*)(w_all + (n0+row)*512 + k0 + col);
        }
        __syncthreads();
        half8 af[4][2], bf[4][2];
        #pragma unroll
        for (int mt=0; mt<4; mt++){
            af[mt][0] = *(const half8*)(&At[wm*64+mt*16+l15][quad*8]);
            af[mt][1] = *(const half8*)(&At[wm*64+mt*16+l15][32+quad*8]);
        }
        #pragma unroll
        for (int nt=0; nt<4; nt++){
            bf[nt][0] = *(const half8*)(&Bt[wn*64+nt*16+l15][quad*8]);
            bf[nt][1] = *(const half8*)(&Bt[wn*64+nt*16+l15][32+quad*8]);
        }
        #pragma unroll
        for (int mt=0; mt<4; mt++)
          #pragma unroll
          for (int nt=0; nt<4; nt++){
            acc[mt][nt] = __builtin_amdgcn_mfma_f32_16x16x32_f16(af[mt][0], bf[nt][0], acc[mt][nt], 0,0,0);
            acc[mt][nt] = __builtin_amdgcn_mfma_f32_16x16x32_f16(af[mt][1], bf[nt][1], acc[mt][nt], 0,0,0);
          }
        __syncthreads();
    }

    float ssc = b2f(scu[1+2*proj]) * b2f(scu[2+2*proj]);
    float qs  = b2f((proj==0)? scu[7] : (proj==1)? scu[8] : scu[11]);
    #pragma unroll
    for (int mt=0; mt<4; mt++){
      #pragma unroll
      for (int nt=0; nt<4; nt++){
        int n = n0 + wn*64 + nt*16 + l15;        // C/D col = lane&15 (verified)
        int nloc = n & 511;
        int h = nloc>>6, d = nloc&63;
        #pragma unroll
        for (int r=0;r<4;r++){
          int m = m0 + wm*64 + mt*16 + quad*4 + r;   // C/D row = quad*4+reg (verified)
          int b = m>>11, s = m&2047;
          int bh = b*8 + h;
          float val = acc[mt][nt][r] * ssc;          // exact integer * scale
          float qv = rintf(clampf(val/qs, -128.f, 127.f));
          if (proj==0)      q16 [(bh*2048 + s)*64 + d] = (_Float16)qv;
          else if (proj==1) k16 [(bh*2048 + s)*64 + d] = (_Float16)qv;
          else              vt16[(bh*64 + d)*2048 + s] = (_Float16)qv;   // transposed
        }
      }
    }
}

// ---------------------------------------------------------------------------
// Fused attention v4: block = 4 waves = one (bh, 64 q-rows); wave w owns
// q rows [q0, q0+16) exclusively. Two passes over t in 128-t chunks with
// block-cooperative double-buffered LDS K staging (R8 structure).
// R9: NO max-tracking — softmax is shift-invariant and scores are bounded
// (|s*al2| <= 75, exp2 safe in fp32), so pass 1 is a pure exp2-sum
// (3 VALU/elem vs 8 with online max) and the merge is plain shuffle-adds.
// Pass 2 folds /l and /s9 into the exponent: p/s9 = exp2(fma(s,al2,lq9)).
// R8 lesson: VALU-issue-bound at 60% — cut ops/elem, not structure.
// R7 lesson: per-wave serial global loads -> exposed latency (staging fixes).
// R4 lesson: register arrays only with compile-time indices.
__global__ __launch_bounds__(256, 3) void k_attn(
    const _Float16* __restrict__ q16, const _Float16* __restrict__ k16,
    const _Float16* __restrict__ vt16, _Float16* __restrict__ o16,
    const unsigned short* __restrict__ scu)
{
    __shared__ __align__(16) _Float16 Kbuf[2][128][72];  // +8 pad (b128-aligned rows)
    __shared__ __align__(16) _Float16 p16[4][16][72];    // per-wave P staging
    int tid = threadIdx.x;
    int w = tid>>6, lane = tid&63, l15 = lane&15, quad = lane>>4;
    int bh = blockIdx.y;
    int q0 = blockIdx.x*64 + w*16;
    float s9 = b2f(scu[9]), s10 = b2f(scu[10]);
    float alpha = b2f(scu[7]) * b2f(scu[8]) * 0.125f;    // DH^-0.5
    float al2 = alpha * 1.44269504088896341f;            // alpha * log2(e)

    f32x4 z = {0.f,0.f,0.f,0.f};
    const _Float16* qr = q16 + (bh*2048 + q0 + l15)*64;
    half8 aq0 = *(const half8*)(qr + quad*8);
    half8 aq1 = *(const half8*)(qr + 32 + quad*8);

    const _Float16* kg    = k16  + bh*131072;
    const _Float16* vbase = vt16 + bh*131072;
    int srow = tid>>3, scol = (tid&7)*8;     // staging coords for this thread

    half8 kst[4];
    #pragma unroll
    for (int i=0;i<4;i++) kst[i] = *(const half8*)(kg + i*2048 + tid*8);  // chunk 0

    float l[4] = {0.f, 0.f, 0.f, 0.f};       // plain exp2-sums (no max shift)

    // ---- pass 1: denominator sums over 16 staged chunks ----
    for (int ch=0; ch<16; ch++){
        int buf = ch & 1;
        #pragma unroll
        for (int i=0;i<4;i++) *(half8*)(&Kbuf[buf][srow + i*32][scol]) = kst[i];
        const _Float16* nsrc = kg + ((ch==15)? 0 : (ch+1))*8192;   // ch15 preloads pass-2 chunk 0
        #pragma unroll
        for (int i=0;i<4;i++) kst[i] = *(const half8*)(nsrc + i*2048 + tid*8);
        __syncthreads();
        #pragma unroll
        for (int sub=0; sub<2; sub++){
            f32x4 s[4];
            #pragma unroll
            for (int j=0;j<4;j++){
                int tt = sub*4 + j;
                half8 bk0 = *(const half8*)(&Kbuf[buf][tt*16+l15][quad*8]);
                half8 bk1 = *(const half8*)(&Kbuf[buf][tt*16+l15][32+quad*8]);
                f32x4 t = __builtin_amdgcn_mfma_f32_16x16x32_f16(aq0, bk0, z, 0,0,0);
                s[j]    = __builtin_amdgcn_mfma_f32_16x16x32_f16(aq1, bk1, t, 0,0,0);
            }
            #pragma unroll
            for (int r=0;r<4;r++){
                float e0 = exp2f(s[0][r]*al2);
                float e1 = exp2f(s[1][r]*al2);
                float e2 = exp2f(s[2][r]*al2);
                float e3 = exp2f(s[3][r]*al2);
                l[r] += (e0+e1) + (e2+e3);
            }
        }
    }

    // merge l across the 16 column lanes (quad preserved: d<16)
    #pragma unroll
    for (int r=0;r<4;r++){
        #pragma unroll
        for (int d=1; d<16; d<<=1)
            l[r] += __shfl_xor(l[r], d, 64);
    }
    float inv_s9 = 1.0f / s9;
    float r910   = s9 / s10;
    float lq9[4];
    #pragma unroll
    for (int r=0;r<4;r++) lq9[r] = log2f(inv_s9 / l[r]);   // fold /l and /s9 into exponent

    // ---- pass 2: recompute scores from re-staged K, quantize P, PV ----
    f32x4 oacc[4];
    #pragma unroll
    for (int dt=0; dt<4; dt++) oacc[dt] = z;
    for (int ch=0; ch<16; ch++){
        int buf = ch & 1;
        #pragma unroll
        for (int i=0;i<4;i++) *(half8*)(&Kbuf[buf][srow + i*32][scol]) = kst[i];
        if (ch < 15){
            const _Float16* nsrc = kg + (ch+1)*8192;
            #pragma unroll
            for (int i=0;i<4;i++) kst[i] = *(const half8*)(nsrc + i*2048 + tid*8);
        }
        __syncthreads();
        // prefetch V fragments for both 64-t subgroups of this chunk
        half8 bva[8], bvb[8];
        #pragma unroll
        for (int dt=0; dt<4; dt++){
            const _Float16* vr0 = vbase + (dt*16+l15)*2048 + ch*128;
            bva[dt*2]   = *(const half8*)(vr0 + quad*8);
            bva[dt*2+1] = *(const half8*)(vr0 + 32 + quad*8);
            bvb[dt*2]   = *(const half8*)(vr0 + 64 + quad*8);
            bvb[dt*2+1] = *(const half8*)(vr0 + 96 + quad*8);
        }
        #pragma unroll
        for (int sub=0; sub<2; sub++){
            f32x4 s[4];
            #pragma unroll
            for (int j=0;j<4;j++){
                int tt = sub*4 + j;
                half8 bk0 = *(const half8*)(&Kbuf[buf][tt*16+l15][quad*8]);
                half8 bk1 = *(const half8*)(&Kbuf[buf][tt*16+l15][32+quad*8]);
                f32x4 t = __builtin_amdgcn_mfma_f32_16x16x32_f16(aq0, bk0, z, 0,0,0);
                s[j]    = __builtin_amdgcn_mfma_f32_16x16x32_f16(aq1, bk1, t, 0,0,0);
            }
            #pragma unroll
            for (int j=0;j<4;j++){
                #pragma unroll
                for (int r=0;r<4;r++){
                    // p/s9 = exp2(s*al2 + log2(1/(s9*l)));  fq(.,s9,0,255) then fq(.,s10)
                    float p1i = rintf(fminf(exp2f(fmaf(s[j][r], al2, lq9[r])), 255.f));
                    float a   = rintf(fminf(p1i*r910, 127.f));
                    p16[w][quad*4+r][j*16+l15] = (_Float16)a;
                }
            }
            half8 ap0 = *(const half8*)(&p16[w][l15][quad*8]);
            half8 ap1 = *(const half8*)(&p16[w][l15][32+quad*8]);
            #pragma unroll
            for (int dt=0; dt<4; dt++){
                half8 b0 = sub ? bvb[dt*2]   : bva[dt*2];
                half8 b1 = sub ? bvb[dt*2+1] : bva[dt*2+1];
                oacc[dt] = __builtin_amdgcn_mfma_f32_16x16x32_f16(ap0, b0, oacc[dt], 0,0,0);
                oacc[dt] = __builtin_amdgcn_mfma_f32_16x16x32_f16(ap1, b1, oacc[dt], 0,0,0);
            }
        }
    }

    // ---- epilogue: quantize with sc12, direct C-layout stores ----
    float s1011 = b2f(scu[10]) * b2f(scu[11]);
    float s12   = b2f(scu[12]);
    int b = bh>>3, h = bh&7;
    #pragma unroll
    for (int dt=0; dt<4; dt++){
        #pragma unroll
        for (int r=0;r<4;r++){
            float o = oacc[dt][r] * s1011;
            _Float16 v = (_Float16)rintf(clampf(o/s12, -128.f, 127.f));
            o16[(b*2048 + q0 + quad*4 + r)*512 + h*64 + dt*16 + l15] = v;
        }
    }
}

// ---------------------------------------------------------------------------
// Output projection: M=8192, N=512, K=512, + bias, bf16 out.
__global__ __launch_bounds__(256) void k_gemm_out(
    const _Float16* __restrict__ o16, const _Float16* __restrict__ wo16,
    const unsigned short* __restrict__ bo, unsigned short* __restrict__ out,
    const unsigned short* __restrict__ scu)
{
    __shared__ __align__(16) _Float16 At[128][64];
    __shared__ __align__(16) _Float16 Bt[128][64];
    int tid = threadIdx.x;
    int m0 = blockIdx.x*128, n0 = blockIdx.y*128;
    int w = tid>>6, lane = tid&63, l15 = lane&15, quad = lane>>4;
    int wm = w>>1, wn = w&1;
    f32x4 z = {0.f,0.f,0.f,0.f};
    f32x4 acc[4][4];
    #pragma unroll
    for (int i=0;i<4;i++)
      #pragma unroll
      for (int j=0;j<4;j++) acc[i][j] = z;

    for (int k0=0; k0<512; k0+=64){
        #pragma unroll
        for (int it=0; it<4; it++){
            int idx = it*256 + tid;
            int row = idx>>3, col = (idx&7)*8;
            *(half8*)(&At[row][col]) = *(const half8*)(o16  + (m0+row)*512 + k0 + col);
            *(half8*)(&Bt[row][col]) = *(const half8*)(wo16 + (n0+row)*512 + k0 + col);
        }
        __syncthreads();
        half8 af[4][2], bf[4][2];
        #pragma unroll
        for (int mt=0; mt<4; mt++){
            af[mt][0] = *(const half8*)(&At[wm*64+mt*16+l15][quad*8]);
            af[mt][1] = *(const half8*)(&At[wm*64+mt*16+l15][32+quad*8]);
        }
        #pragma unroll
        for (int nt=0; nt<4; nt++){
            bf[nt][0] = *(const half8*)(&Bt[wn*64+nt*16+l15][quad*8]);
            bf[nt][1] = *(const half8*)(&Bt[wn*64+nt*16+l15][32+quad*8]);
        }
        #pragma unroll
        for (int mt=0; mt<4; mt++)
          #pragma unroll
          for (int nt=0; nt<4; nt++){
            acc[mt][nt] = __builtin_amdgcn_mfma_f32_16x16x32_f16(af[mt][0], bf[nt][0], acc[mt][nt], 0,0,0);
            acc[mt][nt] = __builtin_amdgcn_mfma_f32_16x16x32_f16(af[mt][1], bf[nt][1], acc[mt][nt], 0,0,0);
          }
        __syncthreads();
    }

    float ssc = b2f(scu[12]) * b2f(scu[13]);
    #pragma unroll
    for (int mt=0; mt<4; mt++){
      #pragma unroll
      for (int nt=0; nt<4; nt++){
        int n = n0 + wn*64 + nt*16 + l15;
        float bn = b2f(bo[n]);
        #pragma unroll
        for (int r=0;r<4;r++){
          int m = m0 + wm*64 + mt*16 + quad*4 + r;
          out[m*512 + n] = f2b(acc[mt][nt][r]*ssc + bn);
        }
      }
    }
}

// ---------------------------------------------------------------------------
extern "C" void kernel_launch(void* const* d_in, const int* in_sizes, int n_in,
                              void* d_out, int out_size, void* d_ws, size_t ws_size,
                              hipStream_t stream)
{
    const unsigned short* hs = (const unsigned short*)d_in[0];
    const unsigned short* Wq = (const unsigned short*)d_in[1];
    const unsigned short* Wk = (const unsigned short*)d_in[2];
    const unsigned short* Wv = (const unsigned short*)d_in[3];
    const unsigned short* Wo = (const unsigned short*)d_in[4];
    const unsigned short* bo = (const unsigned short*)d_in[5];
    const unsigned short* sc = (const unsigned short*)d_in[6];
    unsigned short* out = (unsigned short*)d_out;

    _Float16* wsh   = (_Float16*)d_ws;
    _Float16* w_all = wsh + EW_WALL;
    _Float16* wo16  = wsh + EW_WO;
    _Float16* a_q   = wsh + EW_AQ;
    _Float16* a_k   = wsh + EW_AK;
    _Float16* a_v   = wsh + EW_AV;
    _Float16* q16   = wsh + EW_Q;
    _Float16* k16   = wsh + EW_K;
    _Float16* vt16  = wsh + EW_VT;
    _Float16* o16   = wsh + EW_O;

    k_quant_w<<<512,  256, 0, stream>>>(Wq, Wk, Wv, Wo, w_all, wo16, sc);
    k_quant_a<<<2048, 256, 0, stream>>>(hs, a_q, a_k, a_v, sc);
    k_gemm_qkv<<<dim3(64,12), 256, 0, stream>>>(a_q, a_k, a_v, w_all, q16, k16, vt16, sc);
    k_attn<<<dim3(32,32), 256, 0, stream>>>(q16, k16, vt16, o16, sc);
    k_gemm_out<<<dim3(64,4), 256, 0, stream>>>(o16, wo16, bo, out, sc);
}

// Round 10
// 290.853 us; speedup vs baseline: 1.6278x; 1.0167x over previous
//
#include <hip/hip_runtime.h>

typedef _Float16 half8  __attribute__((ext_vector_type(8)));
typedef float    f32x4  __attribute__((ext_vector_type(4)));
typedef unsigned short ushort8 __attribute__((ext_vector_type(8)));

__device__ __forceinline__ float clampf(float v, float lo, float hi){
    return fminf(fmaxf(v, lo), hi);
}
__device__ __forceinline__ float b2f(unsigned short u){
    unsigned int x = ((unsigned int)u) << 16;
    return __builtin_bit_cast(float, x);
}
__device__ __forceinline__ unsigned short f2b(float f){
    unsigned int u = __builtin_bit_cast(unsigned int, f);
    u += 0x7FFFu + ((u >> 16) & 1u);       // round-to-nearest-even
    return (unsigned short)(u >> 16);
}

// ---------------------------------------------------------------------------
// ws layout in _Float16 ELEMENT offsets (all tensors stored as integer-valued f16)
#define EW_WALL 0u                       // [1536][512] packed Wq/Wk/Wv rows
#define EW_WO   786432u                  // [512][512]
#define EW_AQ   1048576u                 // [8192][512] act for q-proj
#define EW_AK   (EW_AQ + 4194304u)
#define EW_AV   (EW_AK + 4194304u)
#define EW_Q    (EW_AV + 4194304u)       // [bh=32][s=2048][d=64]
#define EW_K    (EW_Q  + 4194304u)       // [bh][s][d]
#define EW_VT   (EW_K  + 4194304u)       // [bh][d=64][s=2048]  (V transposed)
#define EW_O    (EW_VT + 4194304u)       // [8192][512]
// total = 30,408,704 elements = 60,817,408 bytes

// ---------------------------------------------------------------------------
__global__ __launch_bounds__(256) void k_quant_w(
    const unsigned short* __restrict__ Wq, const unsigned short* __restrict__ Wk,
    const unsigned short* __restrict__ Wv, const unsigned short* __restrict__ Wo,
    _Float16* __restrict__ w_all, _Float16* __restrict__ wo16,
    const unsigned short* __restrict__ scu)
{
    int gid  = blockIdx.x * 256 + threadIdx.x;   // 131072 threads, 8 elems each
    int idx8 = gid * 8;
    int which = idx8 >> 18;                      // 262144 elems per matrix
    int rem   = idx8 & 262143;
    const unsigned short* W = (which==0)? Wq : (which==1)? Wk : (which==2)? Wv : Wo;
    float sw = b2f((which<3) ? scu[2 + 2*which] : scu[13]);
    ushort8 w = *(const ushort8*)(W + rem);
    half8 o;
    #pragma unroll
    for (int j=0;j<8;j++)
        o[j] = (_Float16)rintf(clampf(b2f(w[j])/sw, -128.f, 127.f));
    _Float16* dst = (which<3) ? (w_all + which*262144 + rem) : (wo16 + rem);
    *(half8*)dst = o;
}

// ---------------------------------------------------------------------------
__global__ __launch_bounds__(256) void k_quant_a(
    const unsigned short* __restrict__ hs,
    _Float16* __restrict__ aq, _Float16* __restrict__ ak, _Float16* __restrict__ av,
    const unsigned short* __restrict__ scu)
{
    int gid = blockIdx.x * 256 + threadIdx.x;    // 524288 threads, 8 elems each
    int i8 = gid * 8;
    float s0 = b2f(scu[0]), s1 = b2f(scu[1]), s3 = b2f(scu[3]), s5 = b2f(scu[5]);
    ushort8 h = *(const ushort8*)(hs + i8);
    half8 q, k, v;
    #pragma unroll
    for (int j=0;j<8;j++){
        float h1 = rintf(clampf(b2f(h[j])/s0, -128.f, 127.f)) * s0;  // fq(hs, s0)
        q[j] = (_Float16)rintf(clampf(h1/s1, -128.f, 127.f));
        k[j] = (_Float16)rintf(clampf(h1/s3, -128.f, 127.f));
        v[j] = (_Float16)rintf(clampf(h1/s5, -128.f, 127.f));
    }
    *(half8*)(aq+i8) = q;
    *(half8*)(ak+i8) = k;
    *(half8*)(av+i8) = v;
}

// ---------------------------------------------------------------------------
// QKV projection: M=8192, N=1536 (3 projections x 512), K=512. 128x128 tiles,
// 4 waves each doing 64x64 via verified mfma_f32_16x16x32_f16 (exact int math).
__global__ __launch_bounds__(256) void k_gemm_qkv(
    const _Float16* __restrict__ aq, const _Float16* __restrict__ ak,
    const _Float16* __restrict__ av, const _Float16* __restrict__ w_all,
    _Float16* __restrict__ q16, _Float16* __restrict__ k16, _Float16* __restrict__ vt16,
    const unsigned short* __restrict__ scu)
{
    __shared__ __align__(16) _Float16 At[128][64];
    __shared__ __align__(16) _Float16 Bt[128][64];
    int tid = threadIdx.x;
    int m0 = blockIdx.x*128, n0 = blockIdx.y*128;
    int proj = blockIdx.y >> 2;                  // 4 n-blocks per projection
    const _Float16* Ag = (proj==0)? aq : (proj==1)? ak : av;
    int w = tid>>6, lane = tid&63, l15 = lane&15, quad = lane>>4;
    int wm = w>>1, wn = w&1;
    f32x4 z = {0.f,0.f,0.f,0.f};
    f32x4 acc[4][4];
    #pragma unroll
    for (int i=0;i<4;i++)
      #pragma unroll
      for (int j=0;j<4;j++) acc[i][j] = z;

    for (int k0=0; k0<512; k0+=64){
        #pragma unroll
        for (int it=0; it<4; it++){
            int idx = it*256 + tid;              // 0..1023
            int row = idx>>3, col = (idx&7)*8;
            *(half8*)(&At[row][col]) = *(const half8*)(Ag    + (m0+row)*512 + k0 + col);
            *(half8*)(&Bt[row][col]) = *(const half8*)(w_all + (n0+row)*512 + k0 + col);
        }
        __syncthreads();
        half8 af[4][2], bf[4][2];
        #pragma unroll
        for (int mt=0; mt<4; mt++){
            af[mt][0] = *(const half8*)(&At[wm*64+mt*16+l15][quad*8]);
            af[mt][1] = *(const half8*)(&At[wm*64+mt*16+l15][32+quad*8]);
        }
        #pragma unroll
        for (int nt=0; nt<4; nt++){
            bf[nt][0] = *(const half8*)(&Bt[wn*64+nt*16+l15][quad*8]);
            bf[nt][1] = *(const half8*)(&Bt[wn*64+nt*16+l15][32+quad*8]);
        }
        #pragma unroll
        for (int mt=0; mt<4; mt++)
          #pragma unroll
          for (int nt=0; nt<4; nt++){
            acc[mt][nt] = __builtin_amdgcn_mfma_f32_16x16x32_f16(af[mt][0], bf[nt][0], acc[mt][nt], 0,0,0);
            acc[mt][nt] = __builtin_amdgcn_mfma_f32_16x16x32_f16(af[mt][1], bf[nt][1], acc[mt][nt], 0,0,0);
          }
        __syncthreads();
    }

    float ssc = b2f(scu[1+2*proj]) * b2f(scu[2+2*proj]);
    float qs  = b2f((proj==0)? scu[7] : (proj==1)? scu[8] : scu[11]);
    #pragma unroll
    for (int mt=0; mt<4; mt++){
      #pragma unroll
      for (int nt=0; nt<4; nt++){
        int n = n0 + wn*64 + nt*16 + l15;        // C/D col = lane&15 (verified)
        int nloc = n & 511;
        int h = nloc>>6, d = nloc&63;
        #pragma unroll
        for (int r=0;r<4;r++){
          int m = m0 + wm*64 + mt*16 + quad*4 + r;   // C/D row = quad*4+reg (verified)
          int b = m>>11, s = m&2047;
          int bh = b*8 + h;
          float val = acc[mt][nt][r] * ssc;          // exact integer * scale
          float qv = rintf(clampf(val/qs, -128.f, 127.f));
          if (proj==0)      q16 [(bh*2048 + s)*64 + d] = (_Float16)qv;
          else if (proj==1) k16 [(bh*2048 + s)*64 + d] = (_Float16)qv;
          else              vt16[(bh*64 + d)*2048 + s] = (_Float16)qv;   // transposed
        }
      }
    }
}

// ---------------------------------------------------------------------------
// Fused attention v5: block = 4 waves = one (bh, 64 q-rows); wave w owns
// q rows [q0, q0+16) exclusively. Two passes over t in 64-t chunks with
// block-cooperative double-buffered LDS K staging (1 barrier/chunk; the
// chunk-ch reads precede chunk-ch+1's barrier in program order, so the
// chunk-ch+2 overwrite of the same buffer is safe).
// R10: chunk 128->64 halves LDS (46->27.6 KB) -> 5 blocks/CU via
// __launch_bounds__(256,5). R9 analysis: per-CU issue work is only ~35 us;
// the 176 us wall was occupancy-starved latency (2.2 blocks/CU). More
// resident waves is the lever, not fewer ops.
// R9 numerics kept: no max-shift (|s*al2|<=75 safe in fp32), /l and /s9
// folded into exponent. R4: compile-time register indexing only.
__global__ __launch_bounds__(256, 5) void k_attn(
    const _Float16* __restrict__ q16, const _Float16* __restrict__ k16,
    const _Float16* __restrict__ vt16, _Float16* __restrict__ o16,
    const unsigned short* __restrict__ scu)
{
    __shared__ __align__(16) _Float16 Kbuf[2][64][72];   // +8 pad (b128-aligned rows)
    __shared__ __align__(16) _Float16 p16[4][16][72];    // per-wave P staging
    int tid = threadIdx.x;
    int w = tid>>6, lane = tid&63, l15 = lane&15, quad = lane>>4;
    int bh = blockIdx.y;
    int q0 = blockIdx.x*64 + w*16;
    float s9 = b2f(scu[9]), s10 = b2f(scu[10]);
    float alpha = b2f(scu[7]) * b2f(scu[8]) * 0.125f;    // DH^-0.5
    float al2 = alpha * 1.44269504088896341f;            // alpha * log2(e)

    f32x4 z = {0.f,0.f,0.f,0.f};
    const _Float16* qr = q16 + (bh*2048 + q0 + l15)*64;
    half8 aq0 = *(const half8*)(qr + quad*8);
    half8 aq1 = *(const half8*)(qr + 32 + quad*8);

    const _Float16* kg    = k16  + bh*131072;
    const _Float16* vbase = vt16 + bh*131072;
    int srow = tid>>3, scol = (tid&7)*8;     // staging coords (rows 0..31, +32 for i=1)

    half8 kst[2];
    #pragma unroll
    for (int i=0;i<2;i++) kst[i] = *(const half8*)(kg + i*2048 + tid*8);  // chunk 0

    float l[4] = {0.f, 0.f, 0.f, 0.f};       // plain exp2-sums (no max shift)

    // ---- pass 1: denominator sums over 32 staged 64-t chunks ----
    for (int ch=0; ch<32; ch++){
        int buf = ch & 1;
        #pragma unroll
        for (int i=0;i<2;i++) *(half8*)(&Kbuf[buf][srow + i*32][scol]) = kst[i];
        const _Float16* nsrc = kg + ((ch==31)? 0 : (ch+1))*4096;   // ch31 preloads pass-2 chunk 0
        #pragma unroll
        for (int i=0;i<2;i++) kst[i] = *(const half8*)(nsrc + i*2048 + tid*8);
        __syncthreads();
        f32x4 s[4];
        #pragma unroll
        for (int j=0;j<4;j++){
            half8 bk0 = *(const half8*)(&Kbuf[buf][j*16+l15][quad*8]);
            half8 bk1 = *(const half8*)(&Kbuf[buf][j*16+l15][32+quad*8]);
            f32x4 t = __builtin_amdgcn_mfma_f32_16x16x32_f16(aq0, bk0, z, 0,0,0);
            s[j]    = __builtin_amdgcn_mfma_f32_16x16x32_f16(aq1, bk1, t, 0,0,0);
        }
        #pragma unroll
        for (int r=0;r<4;r++){
            float e0 = exp2f(s[0][r]*al2);
            float e1 = exp2f(s[1][r]*al2);
            float e2 = exp2f(s[2][r]*al2);
            float e3 = exp2f(s[3][r]*al2);
            l[r] += (e0+e1) + (e2+e3);
        }
    }

    // merge l across the 16 column lanes (quad preserved: d<16)
    #pragma unroll
    for (int r=0;r<4;r++){
        #pragma unroll
        for (int d=1; d<16; d<<=1)
            l[r] += __shfl_xor(l[r], d, 64);
    }
    float inv_s9 = 1.0f / s9;
    float r910   = s9 / s10;
    float lq9[4];
    #pragma unroll
    for (int r=0;r<4;r++) lq9[r] = log2f(inv_s9 / l[r]);   // fold /l and /s9 into exponent

    // ---- pass 2: recompute scores from re-staged K, quantize P, PV ----
    f32x4 oacc[4];
    #pragma unroll
    for (int dt=0; dt<4; dt++) oacc[dt] = z;
    for (int ch=0; ch<32; ch++){
        int buf = ch & 1;
        #pragma unroll
        for (int i=0;i<2;i++) *(half8*)(&Kbuf[buf][srow + i*32][scol]) = kst[i];
        if (ch < 31){
            const _Float16* nsrc = kg + (ch+1)*4096;
            #pragma unroll
            for (int i=0;i<2;i++) kst[i] = *(const half8*)(nsrc + i*2048 + tid*8);
        }
        __syncthreads();
        // prefetch V fragments for this 64-t chunk
        half8 bv[8];
        #pragma unroll
        for (int dt=0; dt<4; dt++){
            const _Float16* vr0 = vbase + (dt*16+l15)*2048 + ch*64;
            bv[dt*2]   = *(const half8*)(vr0 + quad*8);
            bv[dt*2+1] = *(const half8*)(vr0 + 32 + quad*8);
        }
        f32x4 s[4];
        #pragma unroll
        for (int j=0;j<4;j++){
            half8 bk0 = *(const half8*)(&Kbuf[buf][j*16+l15][quad*8]);
            half8 bk1 = *(const half8*)(&Kbuf[buf][j*16+l15][32+quad*8]);
            f32x4 t = __builtin_amdgcn_mfma_f32_16x16x32_f16(aq0, bk0, z, 0,0,0);
            s[j]    = __builtin_amdgcn_mfma_f32_16x16x32_f16(aq1, bk1, t, 0,0,0);
        }
        #pragma unroll
        for (int j=0;j<4;j++){
            #pragma unroll
            for (int r=0;r<4;r++){
                // p/s9 = exp2(s*al2 + log2(1/(s9*l)));  fq(.,s9,0,255) then fq(.,s10)
                float p1i = rintf(fminf(exp2f(fmaf(s[j][r], al2, lq9[r])), 255.f));
                float a   = rintf(fminf(p1i*r910, 127.f));
                p16[w][quad*4+r][j*16+l15] = (_Float16)a;
            }
        }
        half8 ap0 = *(const half8*)(&p16[w][l15][quad*8]);
        half8 ap1 = *(const half8*)(&p16[w][l15][32+quad*8]);
        #pragma unroll
        for (int dt=0; dt<4; dt++){
            oacc[dt] = __builtin_amdgcn_mfma_f32_16x16x32_f16(ap0, bv[dt*2],   oacc[dt], 0,0,0);
            oacc[dt] = __builtin_amdgcn_mfma_f32_16x16x32_f16(ap1, bv[dt*2+1], oacc[dt], 0,0,0);
        }
    }

    // ---- epilogue: quantize with sc12, direct C-layout stores ----
    float s1011 = b2f(scu[10]) * b2f(scu[11]);
    float s12   = b2f(scu[12]);
    int b = bh>>3, h = bh&7;
    #pragma unroll
    for (int dt=0; dt<4; dt++){
        #pragma unroll
        for (int r=0;r<4;r++){
            float o = oacc[dt][r] * s1011;
            _Float16 v = (_Float16)rintf(clampf(o/s12, -128.f, 127.f));
            o16[(b*2048 + q0 + quad*4 + r)*512 + h*64 + dt*16 + l15] = v;
        }
    }
}

// ---------------------------------------------------------------------------
// Output projection: M=8192, N=512, K=512, + bias, bf16 out.
__global__ __launch_bounds__(256) void k_gemm_out(
    const _Float16* __restrict__ o16, const _Float16* __restrict__ wo16,
    const unsigned short* __restrict__ bo, unsigned short* __restrict__ out,
    const unsigned short* __restrict__ scu)
{
    __shared__ __align__(16) _Float16 At[128][64];
    __shared__ __align__(16) _Float16 Bt[128][64];
    int tid = threadIdx.x;
    int m0 = blockIdx.x*128, n0 = blockIdx.y*128;
    int w = tid>>6, lane = tid&63, l15 = lane&15, quad = lane>>4;
    int wm = w>>1, wn = w&1;
    f32x4 z = {0.f,0.f,0.f,0.f};
    f32x4 acc[4][4];
    #pragma unroll
    for (int i=0;i<4;i++)
      #pragma unroll
      for (int j=0;j<4;j++) acc[i][j] = z;

    for (int k0=0; k0<512; k0+=64){
        #pragma unroll
        for (int it=0; it<4; it++){
            int idx = it*256 + tid;
            int row = idx>>3, col = (idx&7)*8;
            *(half8*)(&At[row][col]) = *(const half8*)(o16  + (m0+row)*512 + k0 + col);
            *(half8*)(&Bt[row][col]) = *(const half8*)(wo16 + (n0+row)*512 + k0 + col);
        }
        __syncthreads();
        half8 af[4][2], bf[4][2];
        #pragma unroll
        for (int mt=0; mt<4; mt++){
            af[mt][0] = *(const half8*)(&At[wm*64+mt*16+l15][quad*8]);
            af[mt][1] = *(const half8*)(&At[wm*64+mt*16+l15][32+quad*8]);
        }
        #pragma unroll
        for (int nt=0; nt<4; nt++){
            bf[nt][0] = *(const half8*)(&Bt[wn*64+nt*16+l15][quad*8]);
            bf[nt][1] = *(const half8*)(&Bt[wn*64+nt*16+l15][32+quad*8]);
        }
        #pragma unroll
        for (int mt=0; mt<4; mt++)
          #pragma unroll
          for (int nt=0; nt<4; nt++){
            acc[mt][nt] = __builtin_amdgcn_mfma_f32_16x16x32_f16(af[mt][0], bf[nt][0], acc[mt][nt], 0,0,0);
            acc[mt][nt] = __builtin_amdgcn_mfma_f32_16x16x32_f16(af[mt][1], bf[nt][1], acc[mt][nt], 0,0,0);
          }
        __syncthreads();
    }

    float ssc = b2f(scu[12]) * b2f(scu[13]);
    #pragma unroll
    for (int mt=0; mt<4; mt++){
      #pragma unroll
      for (int nt=0; nt<4; nt++){
        int n = n0 + wn*64 + nt*16 + l15;
        float bn = b2f(bo[n]);
        #pragma unroll
        for (int r=0;r<4;r++){
          int m = m0 + wm*64 + mt*16 + quad*4 + r;
          out[m*512 + n] = f2b(acc[mt][nt][r]*ssc + bn);
        }
      }
    }
}

// ---------------------------------------------------------------------------
extern "C" void kernel_launch(void* const* d_in, const int* in_sizes, int n_in,
                              void* d_out, int out_size, void* d_ws, size_t ws_size,
                              hipStream_t stream)
{
    const unsigned short* hs = (const unsigned short*)d_in[0];
    const unsigned short* Wq = (const unsigned short*)d_in[1];
    const unsigned short* Wk = (const unsigned short*)d_in[2];
    const unsigned short* Wv = (const unsigned short*)d_in[3];
    const unsigned short* Wo = (const unsigned short*)d_in[4];
    const unsigned short* bo = (const unsigned short*)d_in[5];
    const unsigned short* sc = (const unsigned short*)d_in[6];
    unsigned short* out = (unsigned short*)d_out;

    _Float16* wsh   = (_Float16*)d_ws;
    _Float16* w_all = wsh + EW_WALL;
    _Float16* wo16  = wsh + EW_WO;
    _Float16* a_q   = wsh + EW_AQ;
    _Float16* a_k   = wsh + EW_AK;
    _Float16* a_v   = wsh + EW_AV;
    _Float16* q16   = wsh + EW_Q;
    _Float16* k16   = wsh + EW_K;
    _Float16* vt16  = wsh + EW_VT;
    _Float16* o16   = wsh + EW_O;

    k_quant_w<<<512,  256, 0, stream>>>(Wq, Wk, Wv, Wo, w_all, wo16, sc);
    k_quant_a<<<2048, 256, 0, stream>>>(hs, a_q, a_k, a_v, sc);
    k_gemm_qkv<<<dim3(64,12), 256, 0, stream>>>(a_q, a_k, a_v, w_all, q16, k16, vt16, sc);
    k_attn<<<dim3(32,32), 256, 0, stream>>>(q16, k16, vt16, o16, sc);
    k_gemm_out<<<dim3(64,4), 256, 0, stream>>>(o16, wo16, bo, out, sc);
}

// Round 11
// 276.664 us; speedup vs baseline: 1.7112x; 1.0513x over previous
//
#include <hip/hip_runtime.h>

typedef _Float16 half8  __attribute__((ext_vector_type(8)));
typedef float    f32x4  __attribute__((ext_vector_type(4)));
typedef unsigned short ushort8 __attribute__((ext_vector_type(8)));

__device__ __forceinline__ float clampf(float v, float lo, float hi){
    return fminf(fmaxf(v, lo), hi);
}
__device__ __forceinline__ float b2f(unsigned short u){
    unsigned int x = ((unsigned int)u) << 16;
    return __builtin_bit_cast(float, x);
}
__device__ __forceinline__ unsigned short f2b(float f){
    unsigned int u = __builtin_bit_cast(unsigned int, f);
    u += 0x7FFFu + ((u >> 16) & 1u);       // round-to-nearest-even
    return (unsigned short)(u >> 16);
}
// raw v_exp_f32 (OCML exp2f's safe path costs ~8-10 extra VALU/call; args
// here are bounded |x|<=~80 so the raw instruction is exact enough)
__device__ __forceinline__ float fexp2(float x){ return __builtin_amdgcn_exp2f(x); }

// async global->LDS staging, 16B/lane. LDS dest is wave-uniform base +
// lane*16 (m104/m108 caveat) — our unpadded row layouts are lane-contiguous.
__device__ __forceinline__ void gld_lds16(const _Float16* g, _Float16* lds_uniform){
    __builtin_amdgcn_global_load_lds(
        (const __attribute__((address_space(1))) void*)g,
        (__attribute__((address_space(3))) void*)lds_uniform, 16, 0, 0);
}

// ---------------------------------------------------------------------------
// ws layout in _Float16 ELEMENT offsets (all tensors stored as integer-valued f16)
#define EW_WALL 0u                       // [1536][512] packed Wq/Wk/Wv rows
#define EW_WO   786432u                  // [512][512]
#define EW_AQ   1048576u                 // [8192][512] act for q-proj
#define EW_AK   (EW_AQ + 4194304u)
#define EW_AV   (EW_AK + 4194304u)
#define EW_Q    (EW_AV + 4194304u)       // [bh=32][s=2048][d=64]
#define EW_K    (EW_Q  + 4194304u)       // [bh][s][d]
#define EW_VT   (EW_K  + 4194304u)       // [bh][d=64][s=2048]  (V transposed)
#define EW_O    (EW_VT + 4194304u)       // [8192][512]
// total = 30,408,704 elements = 60,817,408 bytes

// ---------------------------------------------------------------------------
__global__ __launch_bounds__(256) void k_quant_w(
    const unsigned short* __restrict__ Wq, const unsigned short* __restrict__ Wk,
    const unsigned short* __restrict__ Wv, const unsigned short* __restrict__ Wo,
    _Float16* __restrict__ w_all, _Float16* __restrict__ wo16,
    const unsigned short* __restrict__ scu)
{
    int gid  = blockIdx.x * 256 + threadIdx.x;   // 131072 threads, 8 elems each
    int idx8 = gid * 8;
    int which = idx8 >> 18;                      // 262144 elems per matrix
    int rem   = idx8 & 262143;
    const unsigned short* W = (which==0)? Wq : (which==1)? Wk : (which==2)? Wv : Wo;
    float sw = b2f((which<3) ? scu[2 + 2*which] : scu[13]);
    ushort8 w = *(const ushort8*)(W + rem);
    half8 o;
    #pragma unroll
    for (int j=0;j<8;j++)
        o[j] = (_Float16)rintf(clampf(b2f(w[j])/sw, -128.f, 127.f));
    _Float16* dst = (which<3) ? (w_all + which*262144 + rem) : (wo16 + rem);
    *(half8*)dst = o;
}

// ---------------------------------------------------------------------------
__global__ __launch_bounds__(256) void k_quant_a(
    const unsigned short* __restrict__ hs,
    _Float16* __restrict__ aq, _Float16* __restrict__ ak, _Float16* __restrict__ av,
    const unsigned short* __restrict__ scu)
{
    int gid = blockIdx.x * 256 + threadIdx.x;    // 524288 threads, 8 elems each
    int i8 = gid * 8;
    float s0 = b2f(scu[0]), s1 = b2f(scu[1]), s3 = b2f(scu[3]), s5 = b2f(scu[5]);
    ushort8 h = *(const ushort8*)(hs + i8);
    half8 q, k, v;
    #pragma unroll
    for (int j=0;j<8;j++){
        float h1 = rintf(clampf(b2f(h[j])/s0, -128.f, 127.f)) * s0;  // fq(hs, s0)
        q[j] = (_Float16)rintf(clampf(h1/s1, -128.f, 127.f));
        k[j] = (_Float16)rintf(clampf(h1/s3, -128.f, 127.f));
        v[j] = (_Float16)rintf(clampf(h1/s5, -128.f, 127.f));
    }
    *(half8*)(aq+i8) = q;
    *(half8*)(ak+i8) = k;
    *(half8*)(av+i8) = v;
}

// ---------------------------------------------------------------------------
// QKV projection: M=8192, N=1536 (3 projections x 512), K=512. 128x128 tiles,
// mfma_f32_16x16x32_f16 (exact int math). R11: global_load_lds width=16
// staging (m93->m97 lever: removes the VGPR round-trip + staging VALU).
__global__ __launch_bounds__(256) void k_gemm_qkv(
    const _Float16* __restrict__ aq, const _Float16* __restrict__ ak,
    const _Float16* __restrict__ av, const _Float16* __restrict__ w_all,
    _Float16* __restrict__ q16, _Float16* __restrict__ k16, _Float16* __restrict__ vt16,
    const unsigned short* __restrict__ scu)
{
    __shared__ __align__(16) _Float16 At[128][64];
    __shared__ __align__(16) _Float16 Bt[128][64];
    int tid = threadIdx.x;
    int m0 = blockIdx.x*128, n0 = blockIdx.y*128;
    int proj = blockIdx.y >> 2;                  // 4 n-blocks per projection
    const _Float16* Ag = (proj==0)? aq : (proj==1)? ak : av;
    int w = tid>>6, lane = tid&63, l15 = lane&15, quad = lane>>4;
    int wm = w>>1, wn = w&1;
    f32x4 z = {0.f,0.f,0.f,0.f};
    f32x4 acc[4][4];
    #pragma unroll
    for (int i=0;i<4;i++)
      #pragma unroll
      for (int j=0;j<4;j++) acc[i][j] = z;

    for (int k0=0; k0<512; k0+=64){
        #pragma unroll
        for (int it=0; it<4; it++){
            int idx = it*256 + tid;              // 0..1023
            int row = idx>>3, col = (idx&7)*8;   // per-lane global coords
            int ubase = (it*256 + w*64)*8;       // wave-uniform LDS half-offset
            gld_lds16(Ag    + (m0+row)*512 + k0 + col, &At[0][0] + ubase);
            gld_lds16(w_all + (n0+row)*512 + k0 + col, &Bt[0][0] + ubase);
        }
        __syncthreads();
        half8 af[4][2], bf[4][2];
        #pragma unroll
        for (int mt=0; mt<4; mt++){
            af[mt][0] = *(const half8*)(&At[wm*64+mt*16+l15][quad*8]);
            af[mt][1] = *(const half8*)(&At[wm*64+mt*16+l15][32+quad*8]);
        }
        #pragma unroll
        for (int nt=0; nt<4; nt++){
            bf[nt][0] = *(const half8*)(&Bt[wn*64+nt*16+l15][quad*8]);
            bf[nt][1] = *(const half8*)(&Bt[wn*64+nt*16+l15][32+quad*8]);
        }
        #pragma unroll
        for (int mt=0; mt<4; mt++)
          #pragma unroll
          for (int nt=0; nt<4; nt++){
            acc[mt][nt] = __builtin_amdgcn_mfma_f32_16x16x32_f16(af[mt][0], bf[nt][0], acc[mt][nt], 0,0,0);
            acc[mt][nt] = __builtin_amdgcn_mfma_f32_16x16x32_f16(af[mt][1], bf[nt][1], acc[mt][nt], 0,0,0);
          }
        __syncthreads();
    }

    float ssc = b2f(scu[1+2*proj]) * b2f(scu[2+2*proj]);
    float qs  = b2f((proj==0)? scu[7] : (proj==1)? scu[8] : scu[11]);
    #pragma unroll
    for (int mt=0; mt<4; mt++){
      #pragma unroll
      for (int nt=0; nt<4; nt++){
        int n = n0 + wn*64 + nt*16 + l15;        // C/D col = lane&15 (verified)
        int nloc = n & 511;
        int h = nloc>>6, d = nloc&63;
        #pragma unroll
        for (int r=0;r<4;r++){
          int m = m0 + wm*64 + mt*16 + quad*4 + r;   // C/D row = quad*4+reg (verified)
          int b = m>>11, s = m&2047;
          int bh = b*8 + h;
          float val = acc[mt][nt][r] * ssc;          // exact integer * scale
          float qv = rintf(clampf(val/qs, -128.f, 127.f));
          if (proj==0)      q16 [(bh*2048 + s)*64 + d] = (_Float16)qv;
          else if (proj==1) k16 [(bh*2048 + s)*64 + d] = (_Float16)qv;
          else              vt16[(bh*64 + d)*2048 + s] = (_Float16)qv;   // transposed
        }
      }
    }
}

// ---------------------------------------------------------------------------
// Fused attention v6 (= R10 structure + raw v_exp_f32). Block = 4 waves =
// one (bh, 64 q-rows); wave w owns q rows [q0,q0+16). Two passes over t in
// 64-t chunks, double-buffered LDS K staging, 1 barrier/chunk.
// R10 lesson: occupancy is WORK-limited (16 waves/CU total exist) — the
// remaining lever is issue count. exp2f->__builtin_amdgcn_exp2f removes
// OCML's ~8-10 extra VALU per call (1024 calls/wave).
// R9: no max-shift (|s*al2|<=75 fp32-safe); /l,/s9 folded into exponent.
__global__ __launch_bounds__(256, 5) void k_attn(
    const _Float16* __restrict__ q16, const _Float16* __restrict__ k16,
    const _Float16* __restrict__ vt16, _Float16* __restrict__ o16,
    const unsigned short* __restrict__ scu)
{
    __shared__ __align__(16) _Float16 Kbuf[2][64][72];   // +8 pad (b128-aligned rows)
    __shared__ __align__(16) _Float16 p16[4][16][72];    // per-wave P staging
    int tid = threadIdx.x;
    int w = tid>>6, lane = tid&63, l15 = lane&15, quad = lane>>4;
    int bh = blockIdx.y;
    int q0 = blockIdx.x*64 + w*16;
    float s9 = b2f(scu[9]), s10 = b2f(scu[10]);
    float alpha = b2f(scu[7]) * b2f(scu[8]) * 0.125f;    // DH^-0.5
    float al2 = alpha * 1.44269504088896341f;            // alpha * log2(e)

    f32x4 z = {0.f,0.f,0.f,0.f};
    const _Float16* qr = q16 + (bh*2048 + q0 + l15)*64;
    half8 aq0 = *(const half8*)(qr + quad*8);
    half8 aq1 = *(const half8*)(qr + 32 + quad*8);

    const _Float16* kg    = k16  + bh*131072;
    const _Float16* vbase = vt16 + bh*131072;
    int srow = tid>>3, scol = (tid&7)*8;     // staging coords (rows 0..31, +32 for i=1)

    half8 kst[2];
    #pragma unroll
    for (int i=0;i<2;i++) kst[i] = *(const half8*)(kg + i*2048 + tid*8);  // chunk 0

    float l[4] = {0.f, 0.f, 0.f, 0.f};       // plain exp2-sums (no max shift)

    // ---- pass 1: denominator sums over 32 staged 64-t chunks ----
    for (int ch=0; ch<32; ch++){
        int buf = ch & 1;
        #pragma unroll
        for (int i=0;i<2;i++) *(half8*)(&Kbuf[buf][srow + i*32][scol]) = kst[i];
        const _Float16* nsrc = kg + ((ch==31)? 0 : (ch+1))*4096;   // ch31 preloads pass-2 chunk 0
        #pragma unroll
        for (int i=0;i<2;i++) kst[i] = *(const half8*)(nsrc + i*2048 + tid*8);
        __syncthreads();
        f32x4 s[4];
        #pragma unroll
        for (int j=0;j<4;j++){
            half8 bk0 = *(const half8*)(&Kbuf[buf][j*16+l15][quad*8]);
            half8 bk1 = *(const half8*)(&Kbuf[buf][j*16+l15][32+quad*8]);
            f32x4 t = __builtin_amdgcn_mfma_f32_16x16x32_f16(aq0, bk0, z, 0,0,0);
            s[j]    = __builtin_amdgcn_mfma_f32_16x16x32_f16(aq1, bk1, t, 0,0,0);
        }
        #pragma unroll
        for (int r=0;r<4;r++){
            float e0 = fexp2(s[0][r]*al2);
            float e1 = fexp2(s[1][r]*al2);
            float e2 = fexp2(s[2][r]*al2);
            float e3 = fexp2(s[3][r]*al2);
            l[r] += (e0+e1) + (e2+e3);
        }
    }

    // merge l across the 16 column lanes (quad preserved: d<16)
    #pragma unroll
    for (int r=0;r<4;r++){
        #pragma unroll
        for (int d=1; d<16; d<<=1)
            l[r] += __shfl_xor(l[r], d, 64);
    }
    float inv_s9 = 1.0f / s9;
    float r910   = s9 / s10;
    float lq9[4];
    #pragma unroll
    for (int r=0;r<4;r++) lq9[r] = log2f(inv_s9 / l[r]);   // fold /l and /s9 into exponent

    // ---- pass 2: recompute scores from re-staged K, quantize P, PV ----
    f32x4 oacc[4];
    #pragma unroll
    for (int dt=0; dt<4; dt++) oacc[dt] = z;
    for (int ch=0; ch<32; ch++){
        int buf = ch & 1;
        #pragma unroll
        for (int i=0;i<2;i++) *(half8*)(&Kbuf[buf][srow + i*32][scol]) = kst[i];
        if (ch < 31){
            const _Float16* nsrc = kg + (ch+1)*4096;
            #pragma unroll
            for (int i=0;i<2;i++) kst[i] = *(const half8*)(nsrc + i*2048 + tid*8);
        }
        __syncthreads();
        // prefetch V fragments for this 64-t chunk
        half8 bv[8];
        #pragma unroll
        for (int dt=0; dt<4; dt++){
            const _Float16* vr0 = vbase + (dt*16+l15)*2048 + ch*64;
            bv[dt*2]   = *(const half8*)(vr0 + quad*8);
            bv[dt*2+1] = *(const half8*)(vr0 + 32 + quad*8);
        }
        f32x4 s[4];
        #pragma unroll
        for (int j=0;j<4;j++){
            half8 bk0 = *(const half8*)(&Kbuf[buf][j*16+l15][quad*8]);
            half8 bk1 = *(const half8*)(&Kbuf[buf][j*16+l15][32+quad*8]);
            f32x4 t = __builtin_amdgcn_mfma_f32_16x16x32_f16(aq0, bk0, z, 0,0,0);
            s[j]    = __builtin_amdgcn_mfma_f32_16x16x32_f16(aq1, bk1, t, 0,0,0);
        }
        #pragma unroll
        for (int j=0;j<4;j++){
            #pragma unroll
            for (int r=0;r<4;r++){
                // p/s9 = exp2(s*al2 + log2(1/(s9*l)));  fq(.,s9,0,255) then fq(.,s10)
                float p1i = rintf(fminf(fexp2(fmaf(s[j][r], al2, lq9[r])), 255.f));
                float a   = rintf(fminf(p1i*r910, 127.f));
                p16[w][quad*4+r][j*16+l15] = (_Float16)a;
            }
        }
        half8 ap0 = *(const half8*)(&p16[w][l15][quad*8]);
        half8 ap1 = *(const half8*)(&p16[w][l15][32+quad*8]);
        #pragma unroll
        for (int dt=0; dt<4; dt++){
            oacc[dt] = __builtin_amdgcn_mfma_f32_16x16x32_f16(ap0, bv[dt*2],   oacc[dt], 0,0,0);
            oacc[dt] = __builtin_amdgcn_mfma_f32_16x16x32_f16(ap1, bv[dt*2+1], oacc[dt], 0,0,0);
        }
    }

    // ---- epilogue: quantize with sc12, direct C-layout stores ----
    float s1011 = b2f(scu[10]) * b2f(scu[11]);
    float s12   = b2f(scu[12]);
    int b = bh>>3, h = bh&7;
    #pragma unroll
    for (int dt=0; dt<4; dt++){
        #pragma unroll
        for (int r=0;r<4;r++){
            float o = oacc[dt][r] * s1011;
            _Float16 v = (_Float16)rintf(clampf(o/s12, -128.f, 127.f));
            o16[(b*2048 + q0 + quad*4 + r)*512 + h*64 + dt*16 + l15] = v;
        }
    }
}

// ---------------------------------------------------------------------------
// Output projection: M=8192, N=512, K=512, + bias, bf16 out.
// R11: global_load_lds width=16 staging.
__global__ __launch_bounds__(256) void k_gemm_out(
    const _Float16* __restrict__ o16, const _Float16* __restrict__ wo16,
    const unsigned short* __restrict__ bo, unsigned short* __restrict__ out,
    const unsigned short* __restrict__ scu)
{
    __shared__ __align__(16) _Float16 At[128][64];
    __shared__ __align__(16) _Float16 Bt[128][64];
    int tid = threadIdx.x;
    int m0 = blockIdx.x*128, n0 = blockIdx.y*128;
    int w = tid>>6, lane = tid&63, l15 = lane&15, quad = lane>>4;
    int wm = w>>1, wn = w&1;
    f32x4 z = {0.f,0.f,0.f,0.f};
    f32x4 acc[4][4];
    #pragma unroll
    for (int i=0;i<4;i++)
      #pragma unroll
      for (int j=0;j<4;j++) acc[i][j] = z;

    for (int k0=0; k0<512; k0+=64){
        #pragma unroll
        for (int it=0; it<4; it++){
            int idx = it*256 + tid;
            int row = idx>>3, col = (idx&7)*8;
            int ubase = (it*256 + w*64)*8;       // wave-uniform LDS half-offset
            gld_lds16(o16  + (m0+row)*512 + k0 + col, &At[0][0] + ubase);
            gld_lds16(wo16 + (n0+row)*512 + k0 + col, &Bt[0][0] + ubase);
        }
        __syncthreads();
        half8 af[4][2], bf[4][2];
        #pragma unroll
        for (int mt=0; mt<4; mt++){
            af[mt][0] = *(const half8*)(&At[wm*64+mt*16+l15][quad*8]);
            af[mt][1] = *(const half8*)(&At[wm*64+mt*16+l15][32+quad*8]);
        }
        #pragma unroll
        for (int nt=0; nt<4; nt++){
            bf[nt][0] = *(const half8*)(&Bt[wn*64+nt*16+l15][quad*8]);
            bf[nt][1] = *(const half8*)(&Bt[wn*64+nt*16+l15][32+quad*8]);
        }
        #pragma unroll
        for (int mt=0; mt<4; mt++)
          #pragma unroll
          for (int nt=0; nt<4; nt++){
            acc[mt][nt] = __builtin_amdgcn_mfma_f32_16x16x32_f16(af[mt][0], bf[nt][0], acc[mt][nt], 0,0,0);
            acc[mt][nt] = __builtin_amdgcn_mfma_f32_16x16x32_f16(af[mt][1], bf[nt][1], acc[mt][nt], 0,0,0);
          }
        __syncthreads();
    }

    float ssc = b2f(scu[12]) * b2f(scu[13]);
    #pragma unroll
    for (int mt=0; mt<4; mt++){
      #pragma unroll
      for (int nt=0; nt<4; nt++){
        int n = n0 + wn*64 + nt*16 + l15;
        float bn = b2f(bo[n]);
        #pragma unroll
        for (int r=0;r<4;r++){
          int m = m0 + wm*64 + mt*16 + quad*4 + r;
          out[m*512 + n] = f2b(acc[mt][nt][r]*ssc + bn);
        }
      }
    }
}

// ---------------------------------------------------------------------------
extern "C" void kernel_launch(void* const* d_in, const int* in_sizes, int n_in,
                              void* d_out, int out_size, void* d_ws, size_t ws_size,
                              hipStream_t stream)
{
    const unsigned short* hs = (const unsigned short*)d_in[0];
    const unsigned short* Wq = (const unsigned short*)d_in[1];
    const unsigned short* Wk = (const unsigned short*)d_in[2];
    const unsigned short* Wv = (const unsigned short*)d_in[3];
    const unsigned short* Wo = (const unsigned short*)d_in[4];
    const unsigned short* bo = (const unsigned short*)d_in[5];
    const unsigned short* sc = (const unsigned short*)d_in[6];
    unsigned short* out = (unsigned short*)d_out;

    _Float16* wsh   = (_Float16*)d_ws;
    _Float16* w_all = wsh + EW_WALL;
    _Float16* wo16  = wsh + EW_WO;
    _Float16* a_q   = wsh + EW_AQ;
    _Float16* a_k   = wsh + EW_AK;
    _Float16* a_v   = wsh + EW_AV;
    _Float16* q16   = wsh + EW_Q;
    _Float16* k16   = wsh + EW_K;
    _Float16* vt16  = wsh + EW_VT;
    _Float16* o16   = wsh + EW_O;

    k_quant_w<<<512,  256, 0, stream>>>(Wq, Wk, Wv, Wo, w_all, wo16, sc);
    k_quant_a<<<2048, 256, 0, stream>>>(hs, a_q, a_k, a_v, sc);
    k_gemm_qkv<<<dim3(64,12), 256, 0, stream>>>(a_q, a_k, a_v, w_all, q16, k16, vt16, sc);
    k_attn<<<dim3(32,32), 256, 0, stream>>>(q16, k16, vt16, o16, sc);
    k_gemm_out<<<dim3(64,4), 256, 0, stream>>>(o16, wo16, bo, out, sc);
}